// Round 11
// baseline (3002.177 us; speedup 1.0000x reference)
//
#include <hip/hip_runtime.h>
#include <hip/hip_cooperative_groups.h>
#include <math.h>

namespace cg = cooperative_groups;

// Problem constants
#define NQ 12
#define EQ 7
#define SQ 1024
#define TSQ 3
#define DIN 26400
#define BQ 2
#define TQ 4
#define BT 8          // B*T
#define BNN 288       // B*N*N
#define NROWS 2016    // E*BNN
#define G3S 3072      // 3*S
#define BK 32

typedef unsigned short u16;
typedef float f32x4 __attribute__((ext_vector_type(4)));
typedef short s16x8 __attribute__((ext_vector_type(8)));

__device__ __forceinline__ short bh(float f) {
    unsigned u = __float_as_uint(f);
    return (short)((u + 0x8000u) >> 16);
}
__device__ __forceinline__ float b2f(u16 u) {
    return __uint_as_float((unsigned)u << 16);
}
__device__ __forceinline__ s16x8 pack8(float4 a, float4 b) {
    s16x8 r;
    r[0] = bh(a.x); r[1] = bh(a.y); r[2] = bh(a.z); r[3] = bh(a.w);
    r[4] = bh(b.x); r[5] = bh(b.y); r[6] = bh(b.z); r[7] = bh(b.w);
    return r;
}
__device__ __forceinline__ void gload16(const void* g, void* l) {
    __builtin_amdgcn_global_load_lds(
        (const __attribute__((address_space(1))) unsigned*)g,
        (__attribute__((address_space(3))) unsigned*)l, 16, 0, 0);
}
__device__ inline float sigmoidf(float x) { return 1.f / (1.f + expf(-x)); }

// ================= bf16 MFMA GEMM, 64x128 tile: C = A(MxK) * B(NxK)^T =================
template<int AS32, int BS32>
__global__ __launch_bounds__(256)
void gemm_mfma(const void* __restrict__ Ap, long sAb, int lda,
               const void* __restrict__ Bp, long sBb, int ldb,
               const float* __restrict__ bias, long sBiasb,
               float* __restrict__ C, long sCb, int ldc,
               u16* __restrict__ Cb, long sCbb, int ldcb,
               int M, int Nn, int K, int act, int ksplit)
{
    __shared__ __align__(16) u16 lA[2][256][8];
    __shared__ __align__(16) u16 lB[2][512][8];

    const int z = blockIdx.z;
    const int az = z / ksplit;
    const int ks = z - az * ksplit;
    const int Ksl = K / ksplit;
    const int kbase = ks * Ksl;

    const char* Abase = (const char*)Ap + (long)az * sAb * (AS32 ? 4 : 2);
    const char* Bbase = (const char*)Bp + (long)az * sBb * (BS32 ? 4 : 2);

    const int tid = threadIdx.x;
    const int lane = tid & 63;
    const int wave = tid >> 6;
    const int row0 = blockIdx.x * 64;
    const int col0 = blockIdx.y * 128;
    const int wcol = wave * 32;

    const int akg = tid >> 6;
    long arow = row0 + (tid & 63); if (arow >= M) arow = M - 1;
    const int bkg0 = tid >> 7;
    const int s1 = tid + 256;
    const int bkg1 = s1 >> 7;
    long brow0 = col0 + (tid & 127); if (brow0 >= Nn) brow0 = Nn - 1;
    long brow1 = col0 + (s1 & 127);  if (brow1 >= Nn) brow1 = Nn - 1;

    const int arw32 = tid >> 2, akg32 = tid & 3;
    long ar32 = row0 + arw32; if (ar32 >= M) ar32 = M - 1;
    const int brw32 = tid >> 1, bh32 = tid & 1;
    long br32 = col0 + brw32; if (br32 >= Nn) br32 = Nn - 1;

    f32x4 acc[4][2] = {};

#define STAGE(b, kt) do {                                                     \
    const int k0_ = kbase + (kt) * BK;                                        \
    if constexpr (AS32) {                                                     \
        const float* A32 = (const float*)Abase;                               \
        const float* p0 = A32 + ar32 * lda + k0_ + akg32 * 8;                 \
        *(s16x8*)&lA[b][akg32 * 64 + arw32][0] =                              \
            pack8(*(const float4*)p0, *(const float4*)(p0 + 4));              \
    } else {                                                                  \
        const u16* A16 = (const u16*)Abase;                                   \
        gload16(A16 + arow * lda + k0_ + akg * 8, &lA[b][tid][0]);            \
    }                                                                         \
    if constexpr (BS32) {                                                     \
        const float* B32 = (const float*)Bbase;                               \
        const float* q0 = B32 + br32 * ldb + k0_ + bh32 * 16;                 \
        *(s16x8*)&lB[b][(bh32 * 2) * 128 + brw32][0] =                        \
            pack8(*(const float4*)q0, *(const float4*)(q0 + 4));              \
        *(s16x8*)&lB[b][(bh32 * 2 + 1) * 128 + brw32][0] =                    \
            pack8(*(const float4*)(q0 + 8), *(const float4*)(q0 + 12));       \
    } else {                                                                  \
        const u16* B16 = (const u16*)Bbase;                                   \
        gload16(B16 + brow0 * ldb + k0_ + bkg0 * 8, &lB[b][tid][0]);          \
        gload16(B16 + brow1 * ldb + k0_ + bkg1 * 8, &lB[b][s1][0]);           \
    }                                                                         \
} while (0)

#define MFMA_BODY(bufi)                                                       \
    {                                                                         \
        s16x8 af[4], bfr[2];                                                  \
        _Pragma("unroll")                                                     \
        for (int m = 0; m < 4; ++m)                                           \
            af[m] = *(const s16x8*)&lA[bufi][kg * 64 + m * 16 + lr][0];       \
        _Pragma("unroll")                                                     \
        for (int n = 0; n < 2; ++n)                                           \
            bfr[n] = *(const s16x8*)&lB[bufi][kg * 128 + wcol + n * 16 + lr][0]; \
        _Pragma("unroll")                                                     \
        for (int m = 0; m < 4; ++m)                                           \
            _Pragma("unroll")                                                 \
            for (int n = 0; n < 2; ++n)                                       \
                acc[m][n] = __builtin_amdgcn_mfma_f32_16x16x32_bf16(af[m], bfr[n], acc[m][n], 0, 0, 0); \
    }

    const int nk = Ksl / BK;
    const int kg = lane >> 4;
    const int lr = lane & 15;
    int buf = 0;

    STAGE(0, 0);
    if constexpr (!AS32 && !BS32) {
        for (int kt = 0; kt < nk; ++kt) {
            if (kt + 1 < nk) {
                STAGE(buf ^ 1, kt + 1);
                asm volatile("s_waitcnt vmcnt(3)" ::: "memory");
            } else {
                asm volatile("s_waitcnt vmcnt(0)" ::: "memory");
            }
            __builtin_amdgcn_s_barrier();
            __builtin_amdgcn_sched_barrier(0);
            MFMA_BODY(buf);
            __builtin_amdgcn_s_barrier();
            buf ^= 1;
        }
    } else {
        __syncthreads();
        for (int kt = 0; kt < nk; ++kt) {
            if (kt + 1 < nk) STAGE(buf ^ 1, kt + 1);
            MFMA_BODY(buf);
            __syncthreads();
            buf ^= 1;
        }
    }
#undef STAGE
#undef MFMA_BODY

    const int ccol = lane & 15;
    const int crow = (lane >> 4) * 4;
#pragma unroll
    for (int n = 0; n < 2; ++n) {
        const int c = col0 + wcol + n * 16 + ccol;
        const float bv = bias ? bias[(long)az * sBiasb + c] : 0.f;
#pragma unroll
        for (int m = 0; m < 4; ++m) {
            const int rb = row0 + m * 16 + crow;
#pragma unroll
            for (int q = 0; q < 4; ++q) {
                const int r = rb + q;
                if (r >= M) continue;
                float v = acc[m][n][q] + bv;
                if (act == 1) v = 1.f / (1.f + expf(-v));
                else if (act == 2) v = tanhf(v);
                if (C)  C[(long)z * sCb + (long)r * ldc + c] = v;
                if (Cb) Cb[(long)z * sCbb + (long)r * ldcb + c] = (u16)bh(v);
            }
        }
    }
}

// ============ 128x128-tile fp32-in GEMM (Wnm setup) ============
__global__ __launch_bounds__(256)
void gemm128_f32(const float* __restrict__ A, int lda,
                 const float* __restrict__ Bm, int ldb,
                 float* __restrict__ C, long sCb, int ldc,
                 u16* __restrict__ Cb, int ldcb,
                 int M, int Nn, int K, int ksplit)
{
    __shared__ __align__(16) u16 lA[2][512][8];
    __shared__ __align__(16) u16 lB[2][512][8];

    const int ks = blockIdx.z;
    const int Ksl = K / ksplit;
    const int kbase = ks * Ksl;

    const int tid = threadIdx.x;
    const int lane = tid & 63;
    const int wave = tid >> 6;
    const int row0 = blockIdx.x * 128;
    const int col0 = blockIdx.y * 128;
    const int wrow = (wave >> 1) * 64;
    const int wcol = (wave & 1) * 64;

    const int rw = tid >> 1, hf = tid & 1;
    long ar = row0 + rw; if (ar >= M) ar = M - 1;
    long br = col0 + rw; if (br >= Nn) br = Nn - 1;

    f32x4 acc[4][4] = {};

#define STAGE128(b, kt) do {                                                  \
    const int k0_ = kbase + (kt) * BK;                                        \
    const float* p = A + ar * lda + k0_ + hf * 16;                            \
    *(s16x8*)&lA[b][(hf * 2) * 128 + rw][0] =                                 \
        pack8(*(const float4*)p, *(const float4*)(p + 4));                    \
    *(s16x8*)&lA[b][(hf * 2 + 1) * 128 + rw][0] =                             \
        pack8(*(const float4*)(p + 8), *(const float4*)(p + 12));             \
    const float* q = Bm + br * ldb + k0_ + hf * 16;                           \
    *(s16x8*)&lB[b][(hf * 2) * 128 + rw][0] =                                 \
        pack8(*(const float4*)q, *(const float4*)(q + 4));                    \
    *(s16x8*)&lB[b][(hf * 2 + 1) * 128 + rw][0] =                             \
        pack8(*(const float4*)(q + 8), *(const float4*)(q + 12));             \
} while (0)

    const int nk = Ksl / BK;
    STAGE128(0, 0);
    __syncthreads();
    int buf = 0;
    const int kg = lane >> 4;
    const int lr = lane & 15;
    for (int kt = 0; kt < nk; ++kt) {
        if (kt + 1 < nk) STAGE128(buf ^ 1, kt + 1);
        s16x8 af[4], bfr[4];
#pragma unroll
        for (int m = 0; m < 4; ++m)
            af[m] = *(const s16x8*)&lA[buf][kg * 128 + wrow + m * 16 + lr][0];
#pragma unroll
        for (int n = 0; n < 4; ++n)
            bfr[n] = *(const s16x8*)&lB[buf][kg * 128 + wcol + n * 16 + lr][0];
#pragma unroll
        for (int m = 0; m < 4; ++m)
#pragma unroll
            for (int n = 0; n < 4; ++n)
                acc[m][n] = __builtin_amdgcn_mfma_f32_16x16x32_bf16(af[m], bfr[n], acc[m][n], 0, 0, 0);
        __syncthreads();
        buf ^= 1;
    }
#undef STAGE128

    const int ccol = lane & 15;
    const int crow = (lane >> 4) * 4;
#pragma unroll
    for (int n = 0; n < 4; ++n) {
        const int c = col0 + wcol + n * 16 + ccol;
#pragma unroll
        for (int m = 0; m < 4; ++m) {
            const int rb = row0 + wrow + m * 16 + crow;
#pragma unroll
            for (int q = 0; q < 4; ++q) {
                const int r = rb + q;
                if (r >= M) continue;
                float v = acc[m][n][q];
                if (C)  C[(long)ks * sCb + (long)r * ldc + c] = v;
                if (Cb) Cb[(long)r * ldcb + c] = (u16)bh(v);
            }
        }
    }
}

// ============ cooperative GRU scan: tt=0 elementwise + 3x (gh-GEMM + update) + gs fin ============
// Grid MUST be 256 blocks x 512 threads (1 block/CU co-resident; 82 KB LDS).
__global__ __launch_bounds__(512)
void gru_scan(const u16* __restrict__ Whh_b, const float* __restrict__ bhh,
              const u16* __restrict__ Gnm_b, const float* __restrict__ cbias,
              u16* __restrict__ hb0, u16* __restrict__ hb1,
              const float* __restrict__ Wa, const float* __restrict__ ba,
              float* __restrict__ gs_part, float* __restrict__ gs)
{
    cg::grid_group gg = cg::this_grid();

    __shared__ __align__(16) u16 lA[2][1024][8];   // 32KB
    __shared__ __align__(16) u16 lB[2][1536][8];   // 48KB
    __shared__ float rowdot[128];
    __shared__ float red[2][4];

    const int f = blockIdx.x;
    const int tid = threadIdx.x;
    const int lane = tid & 63;
    const int wave = tid >> 6;

    // ======== phase A: tt=0 elementwise (h0 ~ 0: gh0 = bhh; h1 = (1-z)*n) ========
    {
        const int half = tid >> 8;       // 0..1
        const int t2 = tid & 255;
        const int s = t2 * 4;
        for (int pass = 0; pass < 4; ++pass) {
            const int row = pass * 512 + f * 2 + half;
            const bool valid = (row < NROWS);
            float dot = 0.f;
            if (valid) {
                const int e = row / BNN;
                const int r = row % BNN;
                const int b_ = r / 144;
                const int ni = (r / 12) % 12;
                const int mi = r % 12;
                const int bt = b_ * TQ;
                const u16* gnp = Gnm_b + ((long)e * 96 + bt * 12 + ni) * 6144;
                const u16* gmp = Gnm_b + ((long)e * 96 + bt * 12 + mi) * 6144 + G3S;
                ushort4 nR = *(const ushort4*)(gnp + s);
                ushort4 nZ = *(const ushort4*)(gnp + SQ + s);
                ushort4 nN = *(const ushort4*)(gnp + 2 * SQ + s);
                ushort4 mR = *(const ushort4*)(gmp + s);
                ushort4 mZ = *(const ushort4*)(gmp + SQ + s);
                ushort4 mN = *(const ushort4*)(gmp + 2 * SQ + s);
                float4 cbR = *(const float4*)(cbias + s);
                float4 cbZ = *(const float4*)(cbias + SQ + s);
                float4 cbN = *(const float4*)(cbias + 2 * SQ + s);
                float4 bhR = *(const float4*)(bhh + s);
                float4 bhZ = *(const float4*)(bhh + SQ + s);
                float4 bhN = *(const float4*)(bhh + 2 * SQ + s);
                float4 wv  = *(const float4*)(Wa + (long)e * SQ + s);
                float4 hn4;
#define GRU0_COMP(c, u)                                                       \
                {                                                             \
                    float rg = sigmoidf(b2f(nR.u) + b2f(mR.u) + cbR.c + bhR.c); \
                    float zg = sigmoidf(b2f(nZ.u) + b2f(mZ.u) + cbZ.c + bhZ.c); \
                    float nn = tanhf(b2f(nN.u) + b2f(mN.u) + cbN.c + rg * bhN.c); \
                    float hn = (1.f - zg) * nn;                               \
                    hn4.c = hn;                                               \
                    dot += hn * wv.c;                                         \
                }
                GRU0_COMP(x, x) GRU0_COMP(y, y) GRU0_COMP(z, z) GRU0_COMP(w, w)
#undef GRU0_COMP
                ushort4 hb4;
                hb4.x = (u16)bh(hn4.x); hb4.y = (u16)bh(hn4.y);
                hb4.z = (u16)bh(hn4.z); hb4.w = (u16)bh(hn4.w);
                *(ushort4*)(hb0 + (long)row * SQ + s) = hb4;
            }
            for (int off = 32; off > 0; off >>= 1) dot += __shfl_down(dot, off);
            if (lane == 0) red[half][(tid >> 6) & 3] = dot;
            __syncthreads();
            if (valid && t2 == 0) {
                const int e = row / BNN;
                const int r = row % BNN;
                const int b_ = r / 144;
                const int ni = (r / 12) % 12;
                const int mi = r % 12;
                const int bt = b_ * TQ;
                float tot = red[half][0] + red[half][1] + red[half][2] + red[half][3] + ba[e];
                gs[((bt * 12 + ni) * 12 + mi) * EQ + e] = sigmoidf(tot);
            }
            __syncthreads();
        }
    }
    __threadfence();
    gg.sync();
    __threadfence();

    // ======== phase B: tt = 1..3 fused gh-GEMM + GRU update ========
    const int ly = 2 * (f & 7) + ((f >> 3) & 1);   // 0..15 col-tile (XCD swizzle)
    const int lx = f >> 4;                          // 0..15 row-tile
    const int row0 = lx * 128;
    const int col0 = ly * 64;
    const int wr = wave >> 1;
    const int wc = wave & 1;
    const int kg = lane >> 4;
    const int lr = lane & 15;

    long arow = row0 + (tid & 127); if (arow >= NROWS) arow = NROWS - 1;
    const u16* bP[3];
#pragma unroll
    for (int j = 0; j < 3; ++j) {
        const int sB = tid + j * 512;
        const int bk16 = sB / 192;
        const int grow = sB - bk16 * 192;
        bP[j] = Whh_b + (long)((grow >> 6) * SQ + col0 + (grow & 63)) * SQ + bk16 * 8;
    }

    const int ccol = lane & 15;
    const int crow4 = (lane >> 4) * 4;
    int col2[2];
    float cbv[3][2], bhv[3][2];
#pragma unroll
    for (int n = 0; n < 2; ++n) {
        const int c = col0 + wc * 32 + n * 16 + ccol;
        col2[n] = c;
#pragma unroll
        for (int g = 0; g < 3; ++g) {
            cbv[g][n] = cbias[g * SQ + c];
            bhv[g][n] = bhh[g * SQ + c];
        }
    }

    for (int tt = 1; tt <= 3; ++tt) {
        const u16* hin = (tt & 1) ? hb0 : hb1;
        u16* hout = (tt & 1) ? hb1 : hb0;
        const u16* aP0 = hin + arow * SQ + (tid >> 7) * 8;
        const u16* aP1 = aP0 + 32;

        f32x4 acc[3][2][2] = {};

#define GSTAGE(b, kt) do {                                                    \
    const int k0_ = (kt) * 64;                                                \
    gload16(aP0 + k0_, &lA[b][tid][0]);                                       \
    gload16(aP1 + k0_, &lA[b][tid + 512][0]);                                 \
    _Pragma("unroll")                                                         \
    for (int j = 0; j < 3; ++j)                                               \
        gload16(bP[j] + k0_, &lB[b][tid + j * 512][0]);                       \
} while (0)

        GSTAGE(0, 0);
        int buf = 0;
        for (int kt = 0; kt < 16; ++kt) {
            if (kt + 1 < 16) {
                GSTAGE(buf ^ 1, kt + 1);
                asm volatile("s_waitcnt vmcnt(5)" ::: "memory");
            } else {
                asm volatile("s_waitcnt vmcnt(0)" ::: "memory");
            }
            __builtin_amdgcn_s_barrier();
            __builtin_amdgcn_sched_barrier(0);
#pragma unroll
            for (int kk = 0; kk < 2; ++kk) {
                const int k16 = kk * 4 + kg;
                s16x8 af[2], bfr[3][2];
#pragma unroll
                for (int m = 0; m < 2; ++m)
                    af[m] = *(const s16x8*)&lA[buf][k16 * 128 + wr * 32 + m * 16 + lr][0];
#pragma unroll
                for (int g = 0; g < 3; ++g)
#pragma unroll
                    for (int n = 0; n < 2; ++n)
                        bfr[g][n] = *(const s16x8*)&lB[buf][k16 * 192 + g * 64 + wc * 32 + n * 16 + lr][0];
#pragma unroll
                for (int g = 0; g < 3; ++g)
#pragma unroll
                    for (int m = 0; m < 2; ++m)
#pragma unroll
                        for (int n = 0; n < 2; ++n)
                            acc[g][m][n] = __builtin_amdgcn_mfma_f32_16x16x32_bf16(af[m], bfr[g][n], acc[g][m][n], 0, 0, 0);
            }
            __builtin_amdgcn_s_barrier();
            buf ^= 1;
        }
#undef GSTAGE

        if (tid < 128) rowdot[tid] = 0.f;
        __syncthreads();

#pragma unroll
        for (int m = 0; m < 2; ++m) {
#pragma unroll
            for (int q = 0; q < 4; ++q) {
                const int row = row0 + wr * 32 + m * 16 + crow4 + q;
                const bool valid = (row < NROWS);
                float d = 0.f;
                if (valid) {
                    const int e = row / BNN;
                    const int rr = row - e * BNN;
                    const int b_ = rr / 144;
                    const int ni = (rr / 12) % 12;
                    const int mi = rr % 12;
                    const int bt = b_ * TQ + tt;
                    const u16* gnp = Gnm_b + ((long)e * 96 + bt * 12 + ni) * 6144;
                    const u16* gmp = Gnm_b + ((long)e * 96 + bt * 12 + mi) * 6144 + G3S;
                    const float* wap = Wa + (long)e * SQ;
#pragma unroll
                    for (int n = 0; n < 2; ++n) {
                        const int c = col2[n];
                        float gr  = acc[0][m][n][q] + bhv[0][n] + b2f(gnp[c]) + b2f(gmp[c]) + cbv[0][n];
                        float gz  = acc[1][m][n][q] + bhv[1][n] + b2f(gnp[SQ + c]) + b2f(gmp[SQ + c]) + cbv[1][n];
                        float ghn = acc[2][m][n][q] + bhv[2][n];
                        float gin = b2f(gnp[2 * SQ + c]) + b2f(gmp[2 * SQ + c]) + cbv[2][n];
                        float rg = sigmoidf(gr);
                        float zg = sigmoidf(gz);
                        float nn2 = tanhf(gin + rg * ghn);
                        float hp = b2f(hin[(long)row * SQ + c]);
                        float hn = (1.f - zg) * nn2 + zg * hp;
                        hout[(long)row * SQ + c] = (u16)bh(hn);
                        d += hn * wap[c];
                    }
                }
                d += __shfl_xor(d, 1); d += __shfl_xor(d, 2);
                d += __shfl_xor(d, 4); d += __shfl_xor(d, 8);
                if (valid && ccol == 0)
                    atomicAdd(&rowdot[wr * 32 + m * 16 + crow4 + q], d);
            }
        }
        __syncthreads();
        if (tid < 128) {
            const int row = row0 + tid;
            if (row < NROWS) gs_part[((long)tt * 2048 + row) * 16 + ly] = rowdot[tid];
        }
        __threadfence();
        gg.sync();
        __threadfence();
    }

    // ======== phase C: gs finalize for tt=1..3 ========
    {
        const int gidx = f * 512 + tid;
        if (gidx < 3 * 2048) {
            const int tt = 1 + (gidx >> 11);
            const int row = gidx & 2047;
            if (row < NROWS) {
                float sum = 0.f;
#pragma unroll
                for (int j = 0; j < 16; ++j)
                    sum += gs_part[((long)tt * 2048 + row) * 16 + j];
                const int e = row / BNN;
                const int rr = row - e * BNN;
                const int b_ = rr / 144;
                const int ni = (rr / 12) % 12;
                const int mi = rr % 12;
                const int bt = b_ * TQ + tt;
                gs[((bt * 12 + ni) * 12 + mi) * EQ + e] = sigmoidf(sum + ba[e]);
            }
        }
    }
}

// ---------- generic split-K reduce ----------
__global__ __launch_bounds__(256)
void reduce_k(const float* __restrict__ part, int ksplit, int mn, int Nn,
              const float* __restrict__ bias, long sBiasB, int act,
              float* __restrict__ Cf, long sCfB, int ldcf,
              u16* __restrict__ Cb, long sCbB, int ldcb)
{
    int i4 = blockIdx.x * 256 + threadIdx.x;
    int total4 = mn >> 2;
    if (i4 >= total4) return;
    int b = blockIdx.y;
    const float4* p4 = (const float4*)part;
    float4 s = make_float4(0.f, 0.f, 0.f, 0.f);
    for (int ks = 0; ks < ksplit; ++ks) {
        float4 v = p4[(long)(b * ksplit + ks) * total4 + i4];
        s.x += v.x; s.y += v.y; s.z += v.z; s.w += v.w;
    }
    int i = i4 << 2;
    int r = i / Nn, c = i % Nn;
    if (bias) {
        float4 bv = *(const float4*)(bias + (long)b * sBiasB + c);
        s.x += bv.x; s.y += bv.y; s.z += bv.z; s.w += bv.w;
    }
    if (act == 1) {
        s.x = sigmoidf(s.x); s.y = sigmoidf(s.y); s.z = sigmoidf(s.z); s.w = sigmoidf(s.w);
    } else if (act == 2) {
        s.x = tanhf(s.x); s.y = tanhf(s.y); s.z = tanhf(s.z); s.w = tanhf(s.w);
    }
    if (Cf) *(float4*)(Cf + (long)b * sCfB + (long)r * ldcf + c) = s;
    if (Cb) {
        ushort4 o;
        o.x = (u16)bh(s.x); o.y = (u16)bh(s.y); o.z = (u16)bh(s.z); o.w = (u16)bh(s.w);
        *(ushort4*)(Cb + (long)b * sCbB + (long)r * ldcb + c) = o;
    }
}

// ---------- fused rz split-K reduce + sigmoid + ahat + zbuf ----------
__global__ __launch_bounds__(256)
void rz_ahat_k(const float* __restrict__ part, const float* __restrict__ brz,
               const float* __restrict__ prop, u16* __restrict__ amat_b,
               float* __restrict__ zbuf)
{
    int i = blockIdx.x * 256 + threadIdx.x;   // 0..98303
    int rrow = i >> 10, c = i & 1023;
    float sr = 0.f, sz = 0.f;
#pragma unroll
    for (int ks = 0; ks < 8; ++ks) {
        const float* p = part + (long)ks * 196608 + (long)rrow * 2048;
        sr += p[c]; sz += p[1024 + c];
    }
    float r = sigmoidf(sr + brz[c]);
    float z = sigmoidf(sz + brz[1024 + c]);
    amat_b[(long)rrow * 2048 + 1024 + c] = (u16)bh(r * prop[i]);
    zbuf[i] = z;
}

// ---------- fused hhat split-K reduce + tanh + prop update ----------
__global__ __launch_bounds__(256)
void hhat_prop_k(const float* __restrict__ part, const float* __restrict__ bh_,
                 const float* __restrict__ zbuf,
                 float* __restrict__ prop, u16* __restrict__ prop_b)
{
    int i = blockIdx.x * 256 + threadIdx.x;   // 0..98303
    float s = 0.f;
#pragma unroll
    for (int ks = 0; ks < 8; ++ks) s += part[(long)ks * 98304 + i];
    float hhat = tanhf(s + bh_[i & 1023]);
    float z = zbuf[i];
    float v = (1.f - z) * prop[i] + z * hhat;
    prop[i] = v;
    prop_b[i] = (u16)bh(v);
}

// ---------- fused 3-buffer fp32 -> bf16 convert ----------
__global__ void cvt3_bf16_k(const float* __restrict__ s0, u16* __restrict__ d0, int n0,
                            const float* __restrict__ s1, u16* __restrict__ d1, int n1,
                            const float* __restrict__ s2, u16* __restrict__ d2, int n2)
{
    int i = blockIdx.x * 256 + threadIdx.x;
    const float* s; u16* d; int base;
    if (i < n0) { s = s0; d = d0; base = i; }
    else if (i < n0 + n1) { s = s1; d = d1; base = i - n0; }
    else if (i < n0 + n1 + n2) { s = s2; d = d2; base = i - n0 - n1; }
    else return;
    float4 v = ((const float4*)s)[base];
    ushort4 o;
    o.x = (u16)bh(v.x); o.y = (u16)bh(v.y); o.z = (u16)bh(v.z); o.w = (u16)bh(v.w);
    ((ushort4*)d)[base] = o;
}

__global__ __launch_bounds__(256)
void transpose_wc(const float* __restrict__ Wcomp, float* __restrict__ W1T, float* __restrict__ W2T)
{
    __shared__ float t1[32][33];
    __shared__ float t2[32][33];
    const int tx = threadIdx.x & 31;
    const int ty = threadIdx.x >> 5;
    const int d0 = blockIdx.x * 32;
    const int s0 = blockIdx.y * 32;
#pragma unroll
    for (int k = 0; k < 4; ++k) {
        int d = d0 + ty + k * 8;
        t1[ty + k * 8][tx] = Wcomp[(long)d * 2048 + s0 + tx];
        t2[ty + k * 8][tx] = Wcomp[(long)d * 2048 + 1024 + s0 + tx];
    }
    __syncthreads();
#pragma unroll
    for (int k = 0; k < 4; ++k) {
        int s = s0 + ty + k * 8;
        W1T[(long)s * 1024 + d0 + tx] = t1[tx][ty + k * 8];
        W2T[(long)s * 1024 + d0 + tx] = t2[tx][ty + k * 8];
    }
}

__global__ void pack_rz(const float* __restrict__ Wr, const float* __restrict__ Wz,
                        const float* __restrict__ br, const float* __restrict__ bz,
                        u16* __restrict__ Wrz, float* __restrict__ brz)
{
    int i4 = blockIdx.x * 256 + threadIdx.x;
    if (i4 < 512) {
        int c = i4 * 4;
        float4 b = (c < 1024) ? *(const float4*)(br + c) : *(const float4*)(bz + c - 1024);
        *(float4*)(brz + c) = b;
    }
    if (i4 >= 1048576) return;
    int i = i4 * 4;
    int j = i >> 11;
    int c = i & 2047;
    float4 v = (j < 1024) ? *(const float4*)(Wr + (long)j * 2048 + c)
                          : *(const float4*)(Wz + (long)(j - 1024) * 2048 + c);
    ushort4 o;
    o.x = (u16)bh(v.x); o.y = (u16)bh(v.y); o.z = (u16)bh(v.z); o.w = (u16)bh(v.w);
    *(ushort4*)(Wrz + i) = o;
}

__global__ void cbias_k(const float* __restrict__ Wih, const float* __restrict__ bih,
                        const float* __restrict__ bcomp, float* __restrict__ cbias)
{
    int g = blockIdx.x * blockDim.x + threadIdx.x;
    if (g >= G3S) return;
    const float* w = Wih + (long)g * SQ;
    float s = 0.f;
    for (int k = 0; k < SQ; k += 4) {
        float4 wv = *(const float4*)(w + k);
        float4 bv = *(const float4*)(bcomp + k);
        s += wv.x * bv.x + wv.y * bv.y + wv.z * bv.z + wv.w * bv.w;
    }
    cbias[g] = s + bih[g];
}

// ---------------- merged + amat fused ----------------
__global__ __launch_bounds__(256)
void merged_amat_k(const float* __restrict__ gs, const u16* __restrict__ msgs_b,
                   const float* __restrict__ prop, u16* __restrict__ amat_b)
{
    const int bn = blockIdx.x;
    const int bt = bn / 12;
    __shared__ float g[84];
    if (threadIdx.x < 84) g[threadIdx.x] = gs[bn * 84 + threadIdx.x];
    __syncthreads();
    const int s = threadIdx.x * 4;
    float4 acc = make_float4(0.f, 0.f, 0.f, 0.f);
    for (int j = 0; j < 84; ++j) {
        const ushort4 mv = *(const ushort4*)(msgs_b + ((long)(bt * 84 + j)) * SQ + s);
        float gj = g[j];
        acc.x += gj * b2f(mv.x);
        acc.y += gj * b2f(mv.y);
        acc.z += gj * b2f(mv.z);
        acc.w += gj * b2f(mv.w);
    }
    ushort4 o;
    o.x = (u16)bh(acc.x); o.y = (u16)bh(acc.y); o.z = (u16)bh(acc.z); o.w = (u16)bh(acc.w);
    *(ushort4*)(amat_b + (long)bn * 2048 + s) = o;
    float4 pv = *(const float4*)(prop + (long)bn * SQ + s);
    ushort4 o2;
    o2.x = (u16)bh(pv.x); o2.y = (u16)bh(pv.y); o2.z = (u16)bh(pv.z); o2.w = (u16)bh(pv.w);
    *(ushort4*)(amat_b + (long)bn * 2048 + 1024 + s) = o2;
}

// ---------------- final outputs ----------------
__global__ __launch_bounds__(256)
void outputs_k(const float* __restrict__ gs, float* __restrict__ out)
{
    __shared__ float s_act[672];
    __shared__ float s_asum[96];
    int tid = threadIdx.x;
    for (int idx = tid; idx < 672; idx += 256) {
        int bn = idx / 7, e = idx % 7;
        float sum = 0.f;
        for (int m = 0; m < 12; ++m) {
            float g0 = gs[bn * 84 + m * 7];
            sum += (1.f - g0) * gs[bn * 84 + m * 7 + e];
        }
        s_act[idx] = sum;
        out[idx] = sum;
    }
    for (int idx = tid; idx < 96; idx += 256) {
        float a = 0.f;
        for (int m = 0; m < 12; ++m) a += 1.f - gs[idx * 84 + m * 7];
        s_asum[idx] = a;
    }
    for (int idx = tid; idx < 1152; idx += 256) {
        int bn = idx / 12, m = idx % 12;
        out[720 + idx] = 1.f - gs[bn * 84 + m * 7];
    }
    __syncthreads();
    if (tid < 8) {
        float tmp[6];
        float mx = -1e30f;
        for (int e = 1; e < 7; ++e) {
            float sum = 0.f;
            for (int n = 0; n < 12; ++n) {
                int bn = tid * 12 + n;
                sum += s_act[bn * 7 + e] * s_asum[bn];
            }
            tmp[e - 1] = sum;
            mx = fmaxf(mx, sum);
        }
        float den = 0.f;
        for (int e = 0; e < 6; ++e) { tmp[e] = expf(tmp[e] - mx); den += tmp[e]; }
        for (int e = 0; e < 6; ++e) out[672 + tid * 6 + e] = tmp[e] / den;
    }
}

// ---------------- host ----------------
template<int AS32, int BS32>
static void launch_gemm(const void* A, long sAb, int lda,
                        const void* B, long sBb, int ldb,
                        const float* bias, long sBiasb,
                        float* C, long sCb, int ldc,
                        u16* Cb, long sCbb, int ldcb,
                        int M, int Nn, int K, int act, int batch, int ksplit,
                        hipStream_t stream)
{
    dim3 grid((M + 63) / 64, (Nn + 127) / 128, batch * ksplit);
    gemm_mfma<AS32, BS32><<<grid, dim3(256), 0, stream>>>(
        A, sAb, lda, B, sBb, ldb, bias, sBiasb, C, sCb, ldc, Cb, sCbb, ldcb,
        M, Nn, K, act, ksplit);
}

extern "C" void kernel_launch(void* const* d_in, const int* in_sizes, int n_in,
                              void* d_out, int out_size, void* d_ws, size_t ws_size,
                              hipStream_t stream)
{
    const float* pose  = (const float*)d_in[0];
    const float* Wc    = (const float*)d_in[5];
    const float* bc    = (const float*)d_in[6];
    const float* We    = (const float*)d_in[7];
    const float* be    = (const float*)d_in[8];
    const float* Wcomp = (const float*)d_in[9];
    const float* bcomp = (const float*)d_in[10];
    const float* Wr    = (const float*)d_in[11];
    const float* br    = (const float*)d_in[12];
    const float* Wz    = (const float*)d_in[13];
    const float* bz    = (const float*)d_in[14];
    const float* Wh    = (const float*)d_in[15];
    const float* bh_   = (const float*)d_in[16];
    const float* Wih   = (const float*)d_in[17];
    const float* Whh   = (const float*)d_in[18];
    const float* bih   = (const float*)d_in[19];
    const float* bhh   = (const float*)d_in[20];
    const float* Wa    = (const float*)d_in[21];
    const float* ba    = (const float*)d_in[22];

    float* ws = (float*)d_ws;
    // fp32 region
    float* prop    = ws;                    // 98304
    float* cbias   = prop + 98304;          // 3072
    float* scratch = cbias + 3072;          // 8257536  (split-K partials / W1T/W2T)
    float* gs      = scratch + 8257536;     // 8064
    float* zbuf    = gs + 8064;             // 98304
    float* brz     = zbuf + 98304;          // 2048
    float* gs_part = brz + 2048;            // 131072 (4 x 2048 x 16)
    float* fend    = gs_part + 131072;
    // bf16 region
    u16* Whh_b  = (u16*)fend;               // 3145728
    u16* Wnm_b  = Whh_b + 3145728;          // 6291456  (6144 x 1024)
    u16* Wrz_b  = Wnm_b + 6291456;          // 4194304
    u16* Gnm_b  = Wrz_b + 4194304;          // 4128768  (7 x 96 x 6144)
    u16* msgs_b = Gnm_b + 4128768;          // 688128
    u16* h_b0   = msgs_b + 688128;          // 2064384
    u16* h_b1   = h_b0 + 2064384;           // 2064384
    u16* prop_b = h_b1 + 2064384;           // 98304
    u16* amat_b = prop_b + 98304;           // 196608
    u16* pose_b = amat_b + 196608;          // 2534400
    u16* Wc_b   = pose_b + 2534400;         // 27033600

    float* W1T = scratch;                   // transient
    float* W2T = scratch + 1048576;         // transient

    // ---- once per call ----
    hipLaunchKernelGGL(cvt3_bf16_k, dim3(31947), dim3(256), 0, stream,
                       Whh, Whh_b, 786432, pose, pose_b, 633600, Wc, Wc_b, 6758400);
    hipLaunchKernelGGL(cbias_k, dim3(12), dim3(256), 0, stream, Wih, bih, bcomp, cbias);
    hipLaunchKernelGGL(transpose_wc, dim3(32, 32), dim3(256), 0, stream, Wcomp, W1T, W2T);
    hipLaunchKernelGGL(pack_rz, dim3(4096), dim3(256), 0, stream, Wr, Wz, br, bz, Wrz_b, brz);
    gemm128_f32<<<dim3(24, 8, 1), dim3(256), 0, stream>>>(
        Wih, SQ, W1T, SQ, nullptr, 0, SQ, Wnm_b, SQ, G3S, SQ, SQ, 1);
    gemm128_f32<<<dim3(24, 8, 1), dim3(256), 0, stream>>>(
        Wih, SQ, W2T, SQ, nullptr, 0, SQ, Wnm_b + (long)G3S * SQ, SQ, G3S, SQ, SQ, 1);
    // prop = pose @ Wc^T + bc : bf16 operands, ksplit=55
    launch_gemm<0, 0>(pose_b, 0, DIN, Wc_b, 0, DIN, nullptr, 0,
                      scratch, 98304, SQ, nullptr, 0, 0, 96, SQ, DIN, 0, 1, 55, stream);
    hipLaunchKernelGGL(reduce_k, dim3(96, 1), dim3(256), 0, stream,
                       scratch, 55, 98304, SQ, bc, 0L, 0,
                       prop, 0L, SQ, prop_b, 0L, SQ);

    // cooperative gru_scan args (constant across t)
    const u16* gsc_Whh = Whh_b;   const float* gsc_bhh = bhh;
    const u16* gsc_Gnm = Gnm_b;   const float* gsc_cb  = cbias;
    u16* gsc_h0 = h_b0;           u16* gsc_h1 = h_b1;
    const float* gsc_Wa = Wa;     const float* gsc_ba = ba;
    float* gsc_gsp = gs_part;     float* gsc_gs = gs;
    void* gsc_args[] = { (void*)&gsc_Whh, (void*)&gsc_bhh, (void*)&gsc_Gnm, (void*)&gsc_cb,
                         (void*)&gsc_h0, (void*)&gsc_h1, (void*)&gsc_Wa, (void*)&gsc_ba,
                         (void*)&gsc_gsp, (void*)&gsc_gs };

    for (int t = 0; t <= TSQ; ++t) {
        // msgs[bt,n,e,s] = prop @ We[e]^T + be[e] : batch 7, ksplit 4
        launch_gemm<0, 1>(prop_b, 0, SQ, We, (long)SQ * SQ, SQ, nullptr, 0,
                          scratch, 98304, SQ, nullptr, 0, 0, 96, SQ, SQ, 0, EQ, 4, stream);
        hipLaunchKernelGGL(reduce_k, dim3(96, EQ), dim3(256), 0, stream,
                           scratch, 4, 98304, SQ, be, (long)SQ, 0,
                           (float*)nullptr, 0L, 0, msgs_b, (long)SQ, EQ * SQ);
        // Gnm = msgs_e @ Wnm^T : batch 7, direct bf16 write
        launch_gemm<0, 0>(msgs_b, SQ, EQ * SQ, Wnm_b, 0, SQ, nullptr, 0,
                          nullptr, 0, 0, Gnm_b, 589824, 6 * SQ, 96, 6 * SQ, SQ, 0, EQ, 1, stream);
        // GRU scan: ONE cooperative kernel (tt=0..3 + gs finalize)
        hipLaunchCooperativeKernel(gru_scan, dim3(256), dim3(512), gsc_args, 0u, stream);
        if (t < TSQ) {
            hipLaunchKernelGGL(merged_amat_k, dim3(96), dim3(256), 0, stream,
                               gs, msgs_b, prop, amat_b);
            // rz partials : ksplit=8
            launch_gemm<0, 0>(amat_b, 0, 2 * SQ, Wrz_b, 0, 2 * SQ, nullptr, 0,
                              scratch, 196608, 2 * SQ, nullptr, 0, 0, 96, 2 * SQ, 2 * SQ, 0, 1, 8, stream);
            hipLaunchKernelGGL(rz_ahat_k, dim3(384), dim3(256), 0, stream,
                               scratch, brz, prop, amat_b, zbuf);
            // hhat partials : ksplit=8
            launch_gemm<0, 1>(amat_b, 0, 2 * SQ, Wh, 0, 2 * SQ, nullptr, 0,
                              scratch, 98304, SQ, nullptr, 0, 0, 96, SQ, 2 * SQ, 0, 1, 8, stream);
            hipLaunchKernelGGL(hhat_prop_k, dim3(384), dim3(256), 0, stream,
                               scratch, bh_, zbuf, prop, prop_b);
        }
    }

    hipLaunchKernelGGL(outputs_k, dim3(1), dim3(256), 0, stream, gs, (float*)d_out);
}

// Round 12
// 2988.345 us; speedup vs baseline: 1.0046x; 1.0046x over previous
//
#include <hip/hip_runtime.h>
#include <hip/hip_cooperative_groups.h>
#include <math.h>

namespace cg = cooperative_groups;

// Problem constants
#define NQ 12
#define EQ 7
#define SQ 1024
#define TSQ 3
#define DIN 26400
#define BQ 2
#define TQ 4
#define BT 8          // B*T
#define BNN 288       // B*N*N
#define NROWS 2016    // E*BNN
#define G3S 3072      // 3*S
#define BK 32

typedef unsigned short u16;
typedef float f32x4 __attribute__((ext_vector_type(4)));
typedef short s16x8 __attribute__((ext_vector_type(8)));

__device__ __forceinline__ short bh(float f) {
    unsigned u = __float_as_uint(f);
    return (short)((u + 0x8000u) >> 16);
}
__device__ __forceinline__ float b2f(u16 u) {
    return __uint_as_float((unsigned)u << 16);
}
__device__ __forceinline__ s16x8 pack8(float4 a, float4 b) {
    s16x8 r;
    r[0] = bh(a.x); r[1] = bh(a.y); r[2] = bh(a.z); r[3] = bh(a.w);
    r[4] = bh(b.x); r[5] = bh(b.y); r[6] = bh(b.z); r[7] = bh(b.w);
    return r;
}
__device__ __forceinline__ void gload16(const void* g, void* l) {
    __builtin_amdgcn_global_load_lds(
        (const __attribute__((address_space(1))) unsigned*)g,
        (__attribute__((address_space(3))) unsigned*)l, 16, 0, 0);
}
__device__ inline float sigmoidf(float x) { return 1.f / (1.f + expf(-x)); }

// ================= bf16 MFMA GEMM, 64x128 tile: C = A(MxK) * B(NxK)^T =================
template<int AS32, int BS32>
__global__ __launch_bounds__(256)
void gemm_mfma(const void* __restrict__ Ap, long sAb, int lda,
               const void* __restrict__ Bp, long sBb, int ldb,
               const float* __restrict__ bias, long sBiasb,
               float* __restrict__ C, long sCb, int ldc,
               u16* __restrict__ Cb, long sCbb, int ldcb,
               int M, int Nn, int K, int act, int ksplit)
{
    __shared__ __align__(16) u16 lA[2][256][8];
    __shared__ __align__(16) u16 lB[2][512][8];

    const int z = blockIdx.z;
    const int az = z / ksplit;
    const int ks = z - az * ksplit;
    const int Ksl = K / ksplit;
    const int kbase = ks * Ksl;

    const char* Abase = (const char*)Ap + (long)az * sAb * (AS32 ? 4 : 2);
    const char* Bbase = (const char*)Bp + (long)az * sBb * (BS32 ? 4 : 2);

    const int tid = threadIdx.x;
    const int lane = tid & 63;
    const int wave = tid >> 6;
    const int row0 = blockIdx.x * 64;
    const int col0 = blockIdx.y * 128;
    const int wcol = wave * 32;

    const int akg = tid >> 6;
    long arow = row0 + (tid & 63); if (arow >= M) arow = M - 1;
    const int bkg0 = tid >> 7;
    const int s1 = tid + 256;
    const int bkg1 = s1 >> 7;
    long brow0 = col0 + (tid & 127); if (brow0 >= Nn) brow0 = Nn - 1;
    long brow1 = col0 + (s1 & 127);  if (brow1 >= Nn) brow1 = Nn - 1;

    const int arw32 = tid >> 2, akg32 = tid & 3;
    long ar32 = row0 + arw32; if (ar32 >= M) ar32 = M - 1;
    const int brw32 = tid >> 1, bh32 = tid & 1;
    long br32 = col0 + brw32; if (br32 >= Nn) br32 = Nn - 1;

    f32x4 acc[4][2] = {};

#define STAGE(b, kt) do {                                                     \
    const int k0_ = kbase + (kt) * BK;                                        \
    if constexpr (AS32) {                                                     \
        const float* A32 = (const float*)Abase;                               \
        const float* p0 = A32 + ar32 * lda + k0_ + akg32 * 8;                 \
        *(s16x8*)&lA[b][akg32 * 64 + arw32][0] =                              \
            pack8(*(const float4*)p0, *(const float4*)(p0 + 4));              \
    } else {                                                                  \
        const u16* A16 = (const u16*)Abase;                                   \
        gload16(A16 + arow * lda + k0_ + akg * 8, &lA[b][tid][0]);            \
    }                                                                         \
    if constexpr (BS32) {                                                     \
        const float* B32 = (const float*)Bbase;                               \
        const float* q0 = B32 + br32 * ldb + k0_ + bh32 * 16;                 \
        *(s16x8*)&lB[b][(bh32 * 2) * 128 + brw32][0] =                        \
            pack8(*(const float4*)q0, *(const float4*)(q0 + 4));              \
        *(s16x8*)&lB[b][(bh32 * 2 + 1) * 128 + brw32][0] =                    \
            pack8(*(const float4*)(q0 + 8), *(const float4*)(q0 + 12));       \
    } else {                                                                  \
        const u16* B16 = (const u16*)Bbase;                                   \
        gload16(B16 + brow0 * ldb + k0_ + bkg0 * 8, &lB[b][tid][0]);          \
        gload16(B16 + brow1 * ldb + k0_ + bkg1 * 8, &lB[b][s1][0]);           \
    }                                                                         \
} while (0)

#define MFMA_BODY(bufi)                                                       \
    {                                                                         \
        s16x8 af[4], bfr[2];                                                  \
        _Pragma("unroll")                                                     \
        for (int m = 0; m < 4; ++m)                                           \
            af[m] = *(const s16x8*)&lA[bufi][kg * 64 + m * 16 + lr][0];       \
        _Pragma("unroll")                                                     \
        for (int n = 0; n < 2; ++n)                                           \
            bfr[n] = *(const s16x8*)&lB[bufi][kg * 128 + wcol + n * 16 + lr][0]; \
        _Pragma("unroll")                                                     \
        for (int m = 0; m < 4; ++m)                                           \
            _Pragma("unroll")                                                 \
            for (int n = 0; n < 2; ++n)                                       \
                acc[m][n] = __builtin_amdgcn_mfma_f32_16x16x32_bf16(af[m], bfr[n], acc[m][n], 0, 0, 0); \
    }

    const int nk = Ksl / BK;
    const int kg = lane >> 4;
    const int lr = lane & 15;
    int buf = 0;

    STAGE(0, 0);
    if constexpr (!AS32 && !BS32) {
        for (int kt = 0; kt < nk; ++kt) {
            if (kt + 1 < nk) {
                STAGE(buf ^ 1, kt + 1);
                asm volatile("s_waitcnt vmcnt(3)" ::: "memory");
            } else {
                asm volatile("s_waitcnt vmcnt(0)" ::: "memory");
            }
            __builtin_amdgcn_s_barrier();
            __builtin_amdgcn_sched_barrier(0);
            MFMA_BODY(buf);
            __builtin_amdgcn_s_barrier();
            buf ^= 1;
        }
    } else {
        __syncthreads();
        for (int kt = 0; kt < nk; ++kt) {
            if (kt + 1 < nk) STAGE(buf ^ 1, kt + 1);
            MFMA_BODY(buf);
            __syncthreads();
            buf ^= 1;
        }
    }
#undef STAGE
#undef MFMA_BODY

    const int ccol = lane & 15;
    const int crow = (lane >> 4) * 4;
#pragma unroll
    for (int n = 0; n < 2; ++n) {
        const int c = col0 + wcol + n * 16 + ccol;
        const float bv = bias ? bias[(long)az * sBiasb + c] : 0.f;
#pragma unroll
        for (int m = 0; m < 4; ++m) {
            const int rb = row0 + m * 16 + crow;
#pragma unroll
            for (int q = 0; q < 4; ++q) {
                const int r = rb + q;
                if (r >= M) continue;
                float v = acc[m][n][q] + bv;
                if (act == 1) v = 1.f / (1.f + expf(-v));
                else if (act == 2) v = tanhf(v);
                if (C)  C[(long)z * sCb + (long)r * ldc + c] = v;
                if (Cb) Cb[(long)z * sCbb + (long)r * ldcb + c] = (u16)bh(v);
            }
        }
    }
}

// ============ 128x128-tile fp32-in GEMM (Wnm setup) ============
__global__ __launch_bounds__(256)
void gemm128_f32(const float* __restrict__ A, int lda,
                 const float* __restrict__ Bm, int ldb,
                 float* __restrict__ C, long sCb, int ldc,
                 u16* __restrict__ Cb, int ldcb,
                 int M, int Nn, int K, int ksplit)
{
    __shared__ __align__(16) u16 lA[2][512][8];
    __shared__ __align__(16) u16 lB[2][512][8];

    const int ks = blockIdx.z;
    const int Ksl = K / ksplit;
    const int kbase = ks * Ksl;

    const int tid = threadIdx.x;
    const int lane = tid & 63;
    const int wave = tid >> 6;
    const int row0 = blockIdx.x * 128;
    const int col0 = blockIdx.y * 128;
    const int wrow = (wave >> 1) * 64;
    const int wcol = (wave & 1) * 64;

    const int rw = tid >> 1, hf = tid & 1;
    long ar = row0 + rw; if (ar >= M) ar = M - 1;
    long br = col0 + rw; if (br >= Nn) br = Nn - 1;

    f32x4 acc[4][4] = {};

#define STAGE128(b, kt) do {                                                  \
    const int k0_ = kbase + (kt) * BK;                                        \
    const float* p = A + ar * lda + k0_ + hf * 16;                            \
    *(s16x8*)&lA[b][(hf * 2) * 128 + rw][0] =                                 \
        pack8(*(const float4*)p, *(const float4*)(p + 4));                    \
    *(s16x8*)&lA[b][(hf * 2 + 1) * 128 + rw][0] =                             \
        pack8(*(const float4*)(p + 8), *(const float4*)(p + 12));             \
    const float* q = Bm + br * ldb + k0_ + hf * 16;                           \
    *(s16x8*)&lB[b][(hf * 2) * 128 + rw][0] =                                 \
        pack8(*(const float4*)q, *(const float4*)(q + 4));                    \
    *(s16x8*)&lB[b][(hf * 2 + 1) * 128 + rw][0] =                             \
        pack8(*(const float4*)(q + 8), *(const float4*)(q + 12));             \
} while (0)

    const int nk = Ksl / BK;
    STAGE128(0, 0);
    __syncthreads();
    int buf = 0;
    const int kg = lane >> 4;
    const int lr = lane & 15;
    for (int kt = 0; kt < nk; ++kt) {
        if (kt + 1 < nk) STAGE128(buf ^ 1, kt + 1);
        s16x8 af[4], bfr[4];
#pragma unroll
        for (int m = 0; m < 4; ++m)
            af[m] = *(const s16x8*)&lA[buf][kg * 128 + wrow + m * 16 + lr][0];
#pragma unroll
        for (int n = 0; n < 4; ++n)
            bfr[n] = *(const s16x8*)&lB[buf][kg * 128 + wcol + n * 16 + lr][0];
#pragma unroll
        for (int m = 0; m < 4; ++m)
#pragma unroll
            for (int n = 0; n < 4; ++n)
                acc[m][n] = __builtin_amdgcn_mfma_f32_16x16x32_bf16(af[m], bfr[n], acc[m][n], 0, 0, 0);
        __syncthreads();
        buf ^= 1;
    }
#undef STAGE128

    const int ccol = lane & 15;
    const int crow = (lane >> 4) * 4;
#pragma unroll
    for (int n = 0; n < 4; ++n) {
        const int c = col0 + wcol + n * 16 + ccol;
#pragma unroll
        for (int m = 0; m < 4; ++m) {
            const int rb = row0 + wrow + m * 16 + crow;
#pragma unroll
            for (int q = 0; q < 4; ++q) {
                const int r = rb + q;
                if (r >= M) continue;
                float v = acc[m][n][q];
                if (C)  C[(long)ks * sCb + (long)r * ldc + c] = v;
                if (Cb) Cb[(long)r * ldcb + c] = (u16)bh(v);
            }
        }
    }
}

// ============ cooperative GRU scan: tt=0 elementwise + 3x (gh-GEMM + update) + gs fin ============
// Grid MUST be 256 blocks x 512 threads (1 block/CU co-resident; 82 KB LDS).
__global__ __launch_bounds__(512)
void gru_scan(const u16* __restrict__ Whh_b, const float* __restrict__ bhh,
              const u16* __restrict__ Gnm_b, const float* __restrict__ cbias,
              u16* __restrict__ hb0, u16* __restrict__ hb1,
              const float* __restrict__ Wa, const float* __restrict__ ba,
              float* __restrict__ gs_part, float* __restrict__ gs)
{
    cg::grid_group gg = cg::this_grid();

    __shared__ __align__(16) u16 lA[2][1024][8];   // 32KB
    __shared__ __align__(16) u16 lB[2][1536][8];   // 48KB
    __shared__ float rowdot[128];
    __shared__ float red[2][4];

    const int f = blockIdx.x;
    const int tid = threadIdx.x;
    const int lane = tid & 63;
    const int wave = tid >> 6;

    // ======== phase A: tt=0 elementwise (h0 ~ 0: gh0 = bhh; h1 = (1-z)*n) ========
    {
        const int half = tid >> 8;       // 0..1
        const int t2 = tid & 255;
        const int s = t2 * 4;
        for (int pass = 0; pass < 4; ++pass) {
            const int row = pass * 512 + f * 2 + half;
            const bool valid = (row < NROWS);
            float dot = 0.f;
            if (valid) {
                const int e = row / BNN;
                const int r = row % BNN;
                const int b_ = r / 144;
                const int ni = (r / 12) % 12;
                const int mi = r % 12;
                const int bt = b_ * TQ;
                const u16* gnp = Gnm_b + ((long)e * 96 + bt * 12 + ni) * 6144;
                const u16* gmp = Gnm_b + ((long)e * 96 + bt * 12 + mi) * 6144 + G3S;
                ushort4 nR = *(const ushort4*)(gnp + s);
                ushort4 nZ = *(const ushort4*)(gnp + SQ + s);
                ushort4 nN = *(const ushort4*)(gnp + 2 * SQ + s);
                ushort4 mR = *(const ushort4*)(gmp + s);
                ushort4 mZ = *(const ushort4*)(gmp + SQ + s);
                ushort4 mN = *(const ushort4*)(gmp + 2 * SQ + s);
                float4 cbR = *(const float4*)(cbias + s);
                float4 cbZ = *(const float4*)(cbias + SQ + s);
                float4 cbN = *(const float4*)(cbias + 2 * SQ + s);
                float4 bhR = *(const float4*)(bhh + s);
                float4 bhZ = *(const float4*)(bhh + SQ + s);
                float4 bhN = *(const float4*)(bhh + 2 * SQ + s);
                float4 wv  = *(const float4*)(Wa + (long)e * SQ + s);
                float4 hn4;
#define GRU0_COMP(c, u)                                                       \
                {                                                             \
                    float rg = sigmoidf(b2f(nR.u) + b2f(mR.u) + cbR.c + bhR.c); \
                    float zg = sigmoidf(b2f(nZ.u) + b2f(mZ.u) + cbZ.c + bhZ.c); \
                    float nn = tanhf(b2f(nN.u) + b2f(mN.u) + cbN.c + rg * bhN.c); \
                    float hn = (1.f - zg) * nn;                               \
                    hn4.c = hn;                                               \
                    dot += hn * wv.c;                                         \
                }
                GRU0_COMP(x, x) GRU0_COMP(y, y) GRU0_COMP(z, z) GRU0_COMP(w, w)
#undef GRU0_COMP
                ushort4 hb4;
                hb4.x = (u16)bh(hn4.x); hb4.y = (u16)bh(hn4.y);
                hb4.z = (u16)bh(hn4.z); hb4.w = (u16)bh(hn4.w);
                *(ushort4*)(hb0 + (long)row * SQ + s) = hb4;
            }
            for (int off = 32; off > 0; off >>= 1) dot += __shfl_down(dot, off);
            if (lane == 0) red[half][(tid >> 6) & 3] = dot;
            __syncthreads();
            if (valid && t2 == 0) {
                const int e = row / BNN;
                const int r = row % BNN;
                const int b_ = r / 144;
                const int ni = (r / 12) % 12;
                const int mi = r % 12;
                const int bt = b_ * TQ;
                float tot = red[half][0] + red[half][1] + red[half][2] + red[half][3] + ba[e];
                gs[((bt * 12 + ni) * 12 + mi) * EQ + e] = sigmoidf(tot);
            }
            __syncthreads();
        }
    }
    __threadfence();
    gg.sync();
    __threadfence();

    // ======== phase B: tt = 1..3 fused gh-GEMM + GRU update ========
    const int ly = 2 * (f & 7) + ((f >> 3) & 1);   // 0..15 col-tile (XCD swizzle)
    const int lx = f >> 4;                          // 0..15 row-tile
    const int row0 = lx * 128;
    const int col0 = ly * 64;
    const int wr = wave >> 1;
    const int wc = wave & 1;
    const int kg = lane >> 4;
    const int lr = lane & 15;

    long arow = row0 + (tid & 127); if (arow >= NROWS) arow = NROWS - 1;
    const u16* bP[3];
#pragma unroll
    for (int j = 0; j < 3; ++j) {
        const int sB = tid + j * 512;
        const int bk16 = sB / 192;
        const int grow = sB - bk16 * 192;
        bP[j] = Whh_b + (long)((grow >> 6) * SQ + col0 + (grow & 63)) * SQ + bk16 * 8;
    }

    const int ccol = lane & 15;
    const int crow4 = (lane >> 4) * 4;
    int col2[2];
    float cbv[3][2], bhv[3][2];
#pragma unroll
    for (int n = 0; n < 2; ++n) {
        const int c = col0 + wc * 32 + n * 16 + ccol;
        col2[n] = c;
#pragma unroll
        for (int g = 0; g < 3; ++g) {
            cbv[g][n] = cbias[g * SQ + c];
            bhv[g][n] = bhh[g * SQ + c];
        }
    }

    for (int tt = 1; tt <= 3; ++tt) {
        const u16* hin = (tt & 1) ? hb0 : hb1;
        u16* hout = (tt & 1) ? hb1 : hb0;
        const u16* aP0 = hin + arow * SQ + (tid >> 7) * 8;
        const u16* aP1 = aP0 + 32;

        f32x4 acc[3][2][2] = {};

#define GSTAGE(b, kt) do {                                                    \
    const int k0_ = (kt) * 64;                                                \
    gload16(aP0 + k0_, &lA[b][tid][0]);                                       \
    gload16(aP1 + k0_, &lA[b][tid + 512][0]);                                 \
    _Pragma("unroll")                                                         \
    for (int j = 0; j < 3; ++j)                                               \
        gload16(bP[j] + k0_, &lB[b][tid + j * 512][0]);                       \
} while (0)

        GSTAGE(0, 0);
        int buf = 0;
        for (int kt = 0; kt < 16; ++kt) {
            if (kt + 1 < 16) {
                GSTAGE(buf ^ 1, kt + 1);
                asm volatile("s_waitcnt vmcnt(5)" ::: "memory");
            } else {
                asm volatile("s_waitcnt vmcnt(0)" ::: "memory");
            }
            __builtin_amdgcn_s_barrier();
            __builtin_amdgcn_sched_barrier(0);
#pragma unroll
            for (int kk = 0; kk < 2; ++kk) {
                const int k16 = kk * 4 + kg;
                s16x8 af[2], bfr[3][2];
#pragma unroll
                for (int m = 0; m < 2; ++m)
                    af[m] = *(const s16x8*)&lA[buf][k16 * 128 + wr * 32 + m * 16 + lr][0];
#pragma unroll
                for (int g = 0; g < 3; ++g)
#pragma unroll
                    for (int n = 0; n < 2; ++n)
                        bfr[g][n] = *(const s16x8*)&lB[buf][k16 * 192 + g * 64 + wc * 32 + n * 16 + lr][0];
#pragma unroll
                for (int g = 0; g < 3; ++g)
#pragma unroll
                    for (int m = 0; m < 2; ++m)
#pragma unroll
                        for (int n = 0; n < 2; ++n)
                            acc[g][m][n] = __builtin_amdgcn_mfma_f32_16x16x32_bf16(af[m], bfr[g][n], acc[g][m][n], 0, 0, 0);
            }
            __builtin_amdgcn_s_barrier();
            buf ^= 1;
        }
#undef GSTAGE

        if (tid < 128) rowdot[tid] = 0.f;
        __syncthreads();

#pragma unroll
        for (int m = 0; m < 2; ++m) {
#pragma unroll
            for (int q = 0; q < 4; ++q) {
                const int row = row0 + wr * 32 + m * 16 + crow4 + q;
                const bool valid = (row < NROWS);
                float d = 0.f;
                if (valid) {
                    const int e = row / BNN;
                    const int rr = row - e * BNN;
                    const int b_ = rr / 144;
                    const int ni = (rr / 12) % 12;
                    const int mi = rr % 12;
                    const int bt = b_ * TQ + tt;
                    const u16* gnp = Gnm_b + ((long)e * 96 + bt * 12 + ni) * 6144;
                    const u16* gmp = Gnm_b + ((long)e * 96 + bt * 12 + mi) * 6144 + G3S;
                    const float* wap = Wa + (long)e * SQ;
#pragma unroll
                    for (int n = 0; n < 2; ++n) {
                        const int c = col2[n];
                        float gr  = acc[0][m][n][q] + bhv[0][n] + b2f(gnp[c]) + b2f(gmp[c]) + cbv[0][n];
                        float gz  = acc[1][m][n][q] + bhv[1][n] + b2f(gnp[SQ + c]) + b2f(gmp[SQ + c]) + cbv[1][n];
                        float ghn = acc[2][m][n][q] + bhv[2][n];
                        float gin = b2f(gnp[2 * SQ + c]) + b2f(gmp[2 * SQ + c]) + cbv[2][n];
                        float rg = sigmoidf(gr);
                        float zg = sigmoidf(gz);
                        float nn2 = tanhf(gin + rg * ghn);
                        float hp = b2f(hin[(long)row * SQ + c]);
                        float hn = (1.f - zg) * nn2 + zg * hp;
                        hout[(long)row * SQ + c] = (u16)bh(hn);
                        d += hn * wap[c];
                    }
                }
                d += __shfl_xor(d, 1); d += __shfl_xor(d, 2);
                d += __shfl_xor(d, 4); d += __shfl_xor(d, 8);
                if (valid && ccol == 0)
                    atomicAdd(&rowdot[wr * 32 + m * 16 + crow4 + q], d);
            }
        }
        __syncthreads();
        if (tid < 128) {
            const int row = row0 + tid;
            if (row < NROWS) gs_part[((long)tt * 2048 + row) * 16 + ly] = rowdot[tid];
        }
        __threadfence();
        gg.sync();
        __threadfence();
    }

    // ======== phase C: gs finalize for tt=1..3 ========
    {
        const int gidx = f * 512 + tid;
        if (gidx < 3 * 2048) {
            const int tt = 1 + (gidx >> 11);
            const int row = gidx & 2047;
            if (row < NROWS) {
                float sum = 0.f;
#pragma unroll
                for (int j = 0; j < 16; ++j)
                    sum += gs_part[((long)tt * 2048 + row) * 16 + j];
                const int e = row / BNN;
                const int rr = row - e * BNN;
                const int b_ = rr / 144;
                const int ni = (rr / 12) % 12;
                const int mi = rr % 12;
                const int bt = b_ * TQ + tt;
                gs[((bt * 12 + ni) * 12 + mi) * EQ + e] = sigmoidf(sum + ba[e]);
            }
        }
    }
}

// ---------- generic split-K reduce ----------
__global__ __launch_bounds__(256)
void reduce_k(const float* __restrict__ part, int ksplit, int mn, int Nn,
              const float* __restrict__ bias, long sBiasB, int act,
              float* __restrict__ Cf, long sCfB, int ldcf,
              u16* __restrict__ Cb, long sCbB, int ldcb)
{
    int i4 = blockIdx.x * 256 + threadIdx.x;
    int total4 = mn >> 2;
    if (i4 >= total4) return;
    int b = blockIdx.y;
    const float4* p4 = (const float4*)part;
    float4 s = make_float4(0.f, 0.f, 0.f, 0.f);
    for (int ks = 0; ks < ksplit; ++ks) {
        float4 v = p4[(long)(b * ksplit + ks) * total4 + i4];
        s.x += v.x; s.y += v.y; s.z += v.z; s.w += v.w;
    }
    int i = i4 << 2;
    int r = i / Nn, c = i % Nn;
    if (bias) {
        float4 bv = *(const float4*)(bias + (long)b * sBiasB + c);
        s.x += bv.x; s.y += bv.y; s.z += bv.z; s.w += bv.w;
    }
    if (act == 1) {
        s.x = sigmoidf(s.x); s.y = sigmoidf(s.y); s.z = sigmoidf(s.z); s.w = sigmoidf(s.w);
    } else if (act == 2) {
        s.x = tanhf(s.x); s.y = tanhf(s.y); s.z = tanhf(s.z); s.w = tanhf(s.w);
    }
    if (Cf) *(float4*)(Cf + (long)b * sCfB + (long)r * ldcf + c) = s;
    if (Cb) {
        ushort4 o;
        o.x = (u16)bh(s.x); o.y = (u16)bh(s.y); o.z = (u16)bh(s.z); o.w = (u16)bh(s.w);
        *(ushort4*)(Cb + (long)b * sCbB + (long)r * ldcb + c) = o;
    }
}

// ---------- fused rz split-K reduce + sigmoid + ahat + zbuf ----------
__global__ __launch_bounds__(256)
void rz_ahat_k(const float* __restrict__ part, const float* __restrict__ brz,
               const float* __restrict__ prop, u16* __restrict__ amat_b,
               float* __restrict__ zbuf)
{
    int i = blockIdx.x * 256 + threadIdx.x;   // 0..98303
    int rrow = i >> 10, c = i & 1023;
    float sr = 0.f, sz = 0.f;
#pragma unroll
    for (int ks = 0; ks < 8; ++ks) {
        const float* p = part + (long)ks * 196608 + (long)rrow * 2048;
        sr += p[c]; sz += p[1024 + c];
    }
    float r = sigmoidf(sr + brz[c]);
    float z = sigmoidf(sz + brz[1024 + c]);
    amat_b[(long)rrow * 2048 + 1024 + c] = (u16)bh(r * prop[i]);
    zbuf[i] = z;
}

// ---------- fused hhat split-K reduce + tanh + prop update ----------
__global__ __launch_bounds__(256)
void hhat_prop_k(const float* __restrict__ part, const float* __restrict__ bh_,
                 const float* __restrict__ zbuf,
                 float* __restrict__ prop, u16* __restrict__ prop_b)
{
    int i = blockIdx.x * 256 + threadIdx.x;   // 0..98303
    float s = 0.f;
#pragma unroll
    for (int ks = 0; ks < 8; ++ks) s += part[(long)ks * 98304 + i];
    float hhat = tanhf(s + bh_[i & 1023]);
    float z = zbuf[i];
    float v = (1.f - z) * prop[i] + z * hhat;
    prop[i] = v;
    prop_b[i] = (u16)bh(v);
}

// ---------- fused 3-buffer fp32 -> bf16 convert ----------
__global__ void cvt3_bf16_k(const float* __restrict__ s0, u16* __restrict__ d0, int n0,
                            const float* __restrict__ s1, u16* __restrict__ d1, int n1,
                            const float* __restrict__ s2, u16* __restrict__ d2, int n2)
{
    int i = blockIdx.x * 256 + threadIdx.x;
    const float* s; u16* d; int base;
    if (i < n0) { s = s0; d = d0; base = i; }
    else if (i < n0 + n1) { s = s1; d = d1; base = i - n0; }
    else if (i < n0 + n1 + n2) { s = s2; d = d2; base = i - n0 - n1; }
    else return;
    float4 v = ((const float4*)s)[base];
    ushort4 o;
    o.x = (u16)bh(v.x); o.y = (u16)bh(v.y); o.z = (u16)bh(v.z); o.w = (u16)bh(v.w);
    ((ushort4*)d)[base] = o;
}

__global__ __launch_bounds__(256)
void transpose_wc(const float* __restrict__ Wcomp, float* __restrict__ W1T, float* __restrict__ W2T)
{
    __shared__ float t1[32][33];
    __shared__ float t2[32][33];
    const int tx = threadIdx.x & 31;
    const int ty = threadIdx.x >> 5;
    const int d0 = blockIdx.x * 32;
    const int s0 = blockIdx.y * 32;
#pragma unroll
    for (int k = 0; k < 4; ++k) {
        int d = d0 + ty + k * 8;
        t1[ty + k * 8][tx] = Wcomp[(long)d * 2048 + s0 + tx];
        t2[ty + k * 8][tx] = Wcomp[(long)d * 2048 + 1024 + s0 + tx];
    }
    __syncthreads();
#pragma unroll
    for (int k = 0; k < 4; ++k) {
        int s = s0 + ty + k * 8;
        W1T[(long)s * 1024 + d0 + tx] = t1[tx][ty + k * 8];
        W2T[(long)s * 1024 + d0 + tx] = t2[tx][ty + k * 8];
    }
}

__global__ void pack_rz(const float* __restrict__ Wr, const float* __restrict__ Wz,
                        const float* __restrict__ br, const float* __restrict__ bz,
                        u16* __restrict__ Wrz, float* __restrict__ brz)
{
    int i4 = blockIdx.x * 256 + threadIdx.x;
    if (i4 < 512) {
        int c = i4 * 4;
        float4 b = (c < 1024) ? *(const float4*)(br + c) : *(const float4*)(bz + c - 1024);
        *(float4*)(brz + c) = b;
    }
    if (i4 >= 1048576) return;
    int i = i4 * 4;
    int j = i >> 11;
    int c = i & 2047;
    float4 v = (j < 1024) ? *(const float4*)(Wr + (long)j * 2048 + c)
                          : *(const float4*)(Wz + (long)(j - 1024) * 2048 + c);
    ushort4 o;
    o.x = (u16)bh(v.x); o.y = (u16)bh(v.y); o.z = (u16)bh(v.z); o.w = (u16)bh(v.w);
    *(ushort4*)(Wrz + i) = o;
}

__global__ void cbias_k(const float* __restrict__ Wih, const float* __restrict__ bih,
                        const float* __restrict__ bcomp, float* __restrict__ cbias)
{
    int g = blockIdx.x * blockDim.x + threadIdx.x;
    if (g >= G3S) return;
    const float* w = Wih + (long)g * SQ;
    float s = 0.f;
    for (int k = 0; k < SQ; k += 4) {
        float4 wv = *(const float4*)(w + k);
        float4 bv = *(const float4*)(bcomp + k);
        s += wv.x * bv.x + wv.y * bv.y + wv.z * bv.z + wv.w * bv.w;
    }
    cbias[g] = s + bih[g];
}

// ---------------- merged + amat fused ----------------
__global__ __launch_bounds__(256)
void merged_amat_k(const float* __restrict__ gs, const u16* __restrict__ msgs_b,
                   const float* __restrict__ prop, u16* __restrict__ amat_b)
{
    const int bn = blockIdx.x;
    const int bt = bn / 12;
    __shared__ float g[84];
    if (threadIdx.x < 84) g[threadIdx.x] = gs[bn * 84 + threadIdx.x];
    __syncthreads();
    const int s = threadIdx.x * 4;
    float4 acc = make_float4(0.f, 0.f, 0.f, 0.f);
    for (int j = 0; j < 84; ++j) {
        const ushort4 mv = *(const ushort4*)(msgs_b + ((long)(bt * 84 + j)) * SQ + s);
        float gj = g[j];
        acc.x += gj * b2f(mv.x);
        acc.y += gj * b2f(mv.y);
        acc.z += gj * b2f(mv.z);
        acc.w += gj * b2f(mv.w);
    }
    ushort4 o;
    o.x = (u16)bh(acc.x); o.y = (u16)bh(acc.y); o.z = (u16)bh(acc.z); o.w = (u16)bh(acc.w);
    *(ushort4*)(amat_b + (long)bn * 2048 + s) = o;
    float4 pv = *(const float4*)(prop + (long)bn * SQ + s);
    ushort4 o2;
    o2.x = (u16)bh(pv.x); o2.y = (u16)bh(pv.y); o2.z = (u16)bh(pv.z); o2.w = (u16)bh(pv.w);
    *(ushort4*)(amat_b + (long)bn * 2048 + 1024 + s) = o2;
}

// ---------------- final outputs ----------------
__global__ __launch_bounds__(256)
void outputs_k(const float* __restrict__ gs, float* __restrict__ out)
{
    __shared__ float s_act[672];
    __shared__ float s_asum[96];
    int tid = threadIdx.x;
    for (int idx = tid; idx < 672; idx += 256) {
        int bn = idx / 7, e = idx % 7;
        float sum = 0.f;
        for (int m = 0; m < 12; ++m) {
            float g0 = gs[bn * 84 + m * 7];
            sum += (1.f - g0) * gs[bn * 84 + m * 7 + e];
        }
        s_act[idx] = sum;
        out[idx] = sum;
    }
    for (int idx = tid; idx < 96; idx += 256) {
        float a = 0.f;
        for (int m = 0; m < 12; ++m) a += 1.f - gs[idx * 84 + m * 7];
        s_asum[idx] = a;
    }
    for (int idx = tid; idx < 1152; idx += 256) {
        int bn = idx / 12, m = idx % 12;
        out[720 + idx] = 1.f - gs[bn * 84 + m * 7];
    }
    __syncthreads();
    if (tid < 8) {
        float tmp[6];
        float mx = -1e30f;
        for (int e = 1; e < 7; ++e) {
            float sum = 0.f;
            for (int n = 0; n < 12; ++n) {
                int bn = tid * 12 + n;
                sum += s_act[bn * 7 + e] * s_asum[bn];
            }
            tmp[e - 1] = sum;
            mx = fmaxf(mx, sum);
        }
        float den = 0.f;
        for (int e = 0; e < 6; ++e) { tmp[e] = expf(tmp[e] - mx); den += tmp[e]; }
        for (int e = 0; e < 6; ++e) out[672 + tid * 6 + e] = tmp[e] / den;
    }
}

// ---------------- host ----------------
template<int AS32, int BS32>
static void launch_gemm(const void* A, long sAb, int lda,
                        const void* B, long sBb, int ldb,
                        const float* bias, long sBiasb,
                        float* C, long sCb, int ldc,
                        u16* Cb, long sCbb, int ldcb,
                        int M, int Nn, int K, int act, int batch, int ksplit,
                        hipStream_t stream)
{
    dim3 grid((M + 63) / 64, (Nn + 127) / 128, batch * ksplit);
    gemm_mfma<AS32, BS32><<<grid, dim3(256), 0, stream>>>(
        A, sAb, lda, B, sBb, ldb, bias, sBiasb, C, sCb, ldc, Cb, sCbb, ldcb,
        M, Nn, K, act, ksplit);
}

extern "C" void kernel_launch(void* const* d_in, const int* in_sizes, int n_in,
                              void* d_out, int out_size, void* d_ws, size_t ws_size,
                              hipStream_t stream)
{
    const float* pose  = (const float*)d_in[0];
    const float* Wc    = (const float*)d_in[5];
    const float* bc    = (const float*)d_in[6];
    const float* We    = (const float*)d_in[7];
    const float* be    = (const float*)d_in[8];
    const float* Wcomp = (const float*)d_in[9];
    const float* bcomp = (const float*)d_in[10];
    const float* Wr    = (const float*)d_in[11];
    const float* br    = (const float*)d_in[12];
    const float* Wz    = (const float*)d_in[13];
    const float* bz    = (const float*)d_in[14];
    const float* Wh    = (const float*)d_in[15];
    const float* bh_   = (const float*)d_in[16];
    const float* Wih   = (const float*)d_in[17];
    const float* Whh   = (const float*)d_in[18];
    const float* bih   = (const float*)d_in[19];
    const float* bhh   = (const float*)d_in[20];
    const float* Wa    = (const float*)d_in[21];
    const float* ba    = (const float*)d_in[22];

    float* ws = (float*)d_ws;
    // fp32 region
    float* prop    = ws;                    // 98304
    float* cbias   = prop + 98304;          // 3072
    float* scratch = cbias + 3072;          // 8257536  (split-K partials / W1T/W2T)
    float* gs      = scratch + 8257536;     // 8064
    float* zbuf    = gs + 8064;             // 98304
    float* brz     = zbuf + 98304;          // 2048
    float* gs_part = brz + 2048;            // 131072 (4 x 2048 x 16)
    float* fend    = gs_part + 131072;
    // bf16 region
    u16* Whh_b  = (u16*)fend;               // 3145728
    u16* Wnm_b  = Whh_b + 3145728;          // 6291456  (6144 x 1024)
    u16* Wrz_b  = Wnm_b + 6291456;          // 4194304
    u16* Gnm_b  = Wrz_b + 4194304;          // 4128768  (7 x 96 x 6144)
    u16* msgs_b = Gnm_b + 4128768;          // 688128
    u16* h_b0   = msgs_b + 688128;          // 2064384
    u16* h_b1   = h_b0 + 2064384;           // 2064384
    u16* prop_b = h_b1 + 2064384;           // 98304
    u16* amat_b = prop_b + 98304;           // 196608
    u16* pose_b = amat_b + 196608;          // 2534400
    u16* Wc_b   = pose_b + 2534400;         // 27033600

    float* W1T = scratch;                   // transient
    float* W2T = scratch + 1048576;         // transient

    // ---- once per call ----
    hipLaunchKernelGGL(cvt3_bf16_k, dim3(31947), dim3(256), 0, stream,
                       Whh, Whh_b, 786432, pose, pose_b, 633600, Wc, Wc_b, 6758400);
    hipLaunchKernelGGL(cbias_k, dim3(12), dim3(256), 0, stream, Wih, bih, bcomp, cbias);
    hipLaunchKernelGGL(transpose_wc, dim3(32, 32), dim3(256), 0, stream, Wcomp, W1T, W2T);
    hipLaunchKernelGGL(pack_rz, dim3(4096), dim3(256), 0, stream, Wr, Wz, br, bz, Wrz_b, brz);
    gemm128_f32<<<dim3(24, 8, 1), dim3(256), 0, stream>>>(
        Wih, SQ, W1T, SQ, nullptr, 0, SQ, Wnm_b, SQ, G3S, SQ, SQ, 1);
    gemm128_f32<<<dim3(24, 8, 1), dim3(256), 0, stream>>>(
        Wih, SQ, W2T, SQ, nullptr, 0, SQ, Wnm_b + (long)G3S * SQ, SQ, G3S, SQ, SQ, 1);
    // prop = pose @ Wc^T + bc : bf16 operands, ksplit=55
    launch_gemm<0, 0>(pose_b, 0, DIN, Wc_b, 0, DIN, nullptr, 0,
                      scratch, 98304, SQ, nullptr, 0, 0, 96, SQ, DIN, 0, 1, 55, stream);
    hipLaunchKernelGGL(reduce_k, dim3(96, 1), dim3(256), 0, stream,
                       scratch, 55, 98304, SQ, bc, 0L, 0,
                       prop, 0L, SQ, prop_b, 0L, SQ);

    // cooperative gru_scan args (constant across t)
    const u16* gsc_Whh = Whh_b;   const float* gsc_bhh = bhh;
    const u16* gsc_Gnm = Gnm_b;   const float* gsc_cb  = cbias;
    u16* gsc_h0 = h_b0;           u16* gsc_h1 = h_b1;
    const float* gsc_Wa = Wa;     const float* gsc_ba = ba;
    float* gsc_gsp = gs_part;     float* gsc_gs = gs;
    void* gsc_args[] = { (void*)&gsc_Whh, (void*)&gsc_bhh, (void*)&gsc_Gnm, (void*)&gsc_cb,
                         (void*)&gsc_h0, (void*)&gsc_h1, (void*)&gsc_Wa, (void*)&gsc_ba,
                         (void*)&gsc_gsp, (void*)&gsc_gs };

    for (int t = 0; t <= TSQ; ++t) {
        // msgs[bt,n,e,s] = prop @ We[e]^T + be[e] : batch 7, ksplit 4
        launch_gemm<0, 1>(prop_b, 0, SQ, We, (long)SQ * SQ, SQ, nullptr, 0,
                          scratch, 98304, SQ, nullptr, 0, 0, 96, SQ, SQ, 0, EQ, 4, stream);
        hipLaunchKernelGGL(reduce_k, dim3(96, EQ), dim3(256), 0, stream,
                           scratch, 4, 98304, SQ, be, (long)SQ, 0,
                           (float*)nullptr, 0L, 0, msgs_b, (long)SQ, EQ * SQ);
        // Gnm = msgs_e @ Wnm^T : batch 7, direct bf16 write
        launch_gemm<0, 0>(msgs_b, SQ, EQ * SQ, Wnm_b, 0, SQ, nullptr, 0,
                          nullptr, 0, 0, Gnm_b, 589824, 6 * SQ, 96, 6 * SQ, SQ, 0, EQ, 1, stream);
        // GRU scan: ONE cooperative kernel (tt=0..3 + gs finalize)
        hipLaunchCooperativeKernel(gru_scan, dim3(256), dim3(512), gsc_args, 0u, stream);
        if (t < TSQ) {
            hipLaunchKernelGGL(merged_amat_k, dim3(96), dim3(256), 0, stream,
                               gs, msgs_b, prop, amat_b);
            // rz partials : ksplit=8
            launch_gemm<0, 0>(amat_b, 0, 2 * SQ, Wrz_b, 0, 2 * SQ, nullptr, 0,
                              scratch, 196608, 2 * SQ, nullptr, 0, 0, 96, 2 * SQ, 2 * SQ, 0, 1, 8, stream);
            hipLaunchKernelGGL(rz_ahat_k, dim3(384), dim3(256), 0, stream,
                               scratch, brz, prop, amat_b, zbuf);
            // hhat partials : ksplit=8
            launch_gemm<0, 1>(amat_b, 0, 2 * SQ, Wh, 0, 2 * SQ, nullptr, 0,
                              scratch, 98304, SQ, nullptr, 0, 0, 96, SQ, 2 * SQ, 0, 1, 8, stream);
            hipLaunchKernelGGL(hhat_prop_k, dim3(384), dim3(256), 0, stream,
                               scratch, bh_, zbuf, prop, prop_b);
        }
    }

    hipLaunchKernelGGL(outputs_k, dim3(1), dim3(256), 0, stream, gs, (float*)d_out);
}

// Round 13
// 1119.023 us; speedup vs baseline: 2.6829x; 2.6705x over previous
//
#include <hip/hip_runtime.h>
#include <math.h>

// Problem constants
#define NQ 12
#define EQ 7
#define SQ 1024
#define TSQ 3
#define DIN 26400
#define BQ 2
#define TQ 4
#define BT 8          // B*T
#define BNN 288       // B*N*N
#define NROWS 2016    // E*BNN
#define G3S 3072      // 3*S
#define BK 32

typedef unsigned short u16;
typedef float f32x4 __attribute__((ext_vector_type(4)));
typedef short s16x8 __attribute__((ext_vector_type(8)));

__device__ __forceinline__ short bh(float f) {
    unsigned u = __float_as_uint(f);
    return (short)((u + 0x8000u) >> 16);
}
__device__ __forceinline__ float b2f(u16 u) {
    return __uint_as_float((unsigned)u << 16);
}
__device__ __forceinline__ s16x8 pack8(float4 a, float4 b) {
    s16x8 r;
    r[0] = bh(a.x); r[1] = bh(a.y); r[2] = bh(a.z); r[3] = bh(a.w);
    r[4] = bh(b.x); r[5] = bh(b.y); r[6] = bh(b.z); r[7] = bh(b.w);
    return r;
}
__device__ __forceinline__ void gload16(const void* g, void* l) {
    __builtin_amdgcn_global_load_lds(
        (const __attribute__((address_space(1))) unsigned*)g,
        (__attribute__((address_space(3))) unsigned*)l, 16, 0, 0);
}
__device__ inline float sigmoidf(float x) { return 1.f / (1.f + expf(-x)); }

// ================= bf16 MFMA GEMM, 64x128 tile: C = A(MxK) * B(NxK)^T =================
template<int AS32, int BS32>
__global__ __launch_bounds__(256)
void gemm_mfma(const void* __restrict__ Ap, long sAb, int lda,
               const void* __restrict__ Bp, long sBb, int ldb,
               const float* __restrict__ bias, long sBiasb,
               float* __restrict__ C, long sCb, int ldc,
               u16* __restrict__ Cb, long sCbb, int ldcb,
               int M, int Nn, int K, int act, int ksplit)
{
    __shared__ __align__(16) u16 lA[2][256][8];
    __shared__ __align__(16) u16 lB[2][512][8];

    const int z = blockIdx.z;
    const int az = z / ksplit;
    const int ks = z - az * ksplit;
    const int Ksl = K / ksplit;
    const int kbase = ks * Ksl;

    const char* Abase = (const char*)Ap + (long)az * sAb * (AS32 ? 4 : 2);
    const char* Bbase = (const char*)Bp + (long)az * sBb * (BS32 ? 4 : 2);

    const int tid = threadIdx.x;
    const int lane = tid & 63;
    const int wave = tid >> 6;
    const int row0 = blockIdx.x * 64;
    const int col0 = blockIdx.y * 128;
    const int wcol = wave * 32;

    const int akg = tid >> 6;
    long arow = row0 + (tid & 63); if (arow >= M) arow = M - 1;
    const int bkg0 = tid >> 7;
    const int s1 = tid + 256;
    const int bkg1 = s1 >> 7;
    long brow0 = col0 + (tid & 127); if (brow0 >= Nn) brow0 = Nn - 1;
    long brow1 = col0 + (s1 & 127);  if (brow1 >= Nn) brow1 = Nn - 1;

    const int arw32 = tid >> 2, akg32 = tid & 3;
    long ar32 = row0 + arw32; if (ar32 >= M) ar32 = M - 1;
    const int brw32 = tid >> 1, bh32 = tid & 1;
    long br32 = col0 + brw32; if (br32 >= Nn) br32 = Nn - 1;

    f32x4 acc[4][2] = {};

#define STAGE(b, kt) do {                                                     \
    const int k0_ = kbase + (kt) * BK;                                        \
    if constexpr (AS32) {                                                     \
        const float* A32 = (const float*)Abase;                               \
        const float* p0 = A32 + ar32 * lda + k0_ + akg32 * 8;                 \
        *(s16x8*)&lA[b][akg32 * 64 + arw32][0] =                              \
            pack8(*(const float4*)p0, *(const float4*)(p0 + 4));              \
    } else {                                                                  \
        const u16* A16 = (const u16*)Abase;                                   \
        gload16(A16 + arow * lda + k0_ + akg * 8, &lA[b][tid][0]);            \
    }                                                                         \
    if constexpr (BS32) {                                                     \
        const float* B32 = (const float*)Bbase;                               \
        const float* q0 = B32 + br32 * ldb + k0_ + bh32 * 16;                 \
        *(s16x8*)&lB[b][(bh32 * 2) * 128 + brw32][0] =                        \
            pack8(*(const float4*)q0, *(const float4*)(q0 + 4));              \
        *(s16x8*)&lB[b][(bh32 * 2 + 1) * 128 + brw32][0] =                    \
            pack8(*(const float4*)(q0 + 8), *(const float4*)(q0 + 12));       \
    } else {                                                                  \
        const u16* B16 = (const u16*)Bbase;                                   \
        gload16(B16 + brow0 * ldb + k0_ + bkg0 * 8, &lB[b][tid][0]);          \
        gload16(B16 + brow1 * ldb + k0_ + bkg1 * 8, &lB[b][s1][0]);           \
    }                                                                         \
} while (0)

#define MFMA_BODY(bufi)                                                       \
    {                                                                         \
        s16x8 af[4], bfr[2];                                                  \
        _Pragma("unroll")                                                     \
        for (int m = 0; m < 4; ++m)                                           \
            af[m] = *(const s16x8*)&lA[bufi][kg * 64 + m * 16 + lr][0];       \
        _Pragma("unroll")                                                     \
        for (int n = 0; n < 2; ++n)                                           \
            bfr[n] = *(const s16x8*)&lB[bufi][kg * 128 + wcol + n * 16 + lr][0]; \
        _Pragma("unroll")                                                     \
        for (int m = 0; m < 4; ++m)                                           \
            _Pragma("unroll")                                                 \
            for (int n = 0; n < 2; ++n)                                       \
                acc[m][n] = __builtin_amdgcn_mfma_f32_16x16x32_bf16(af[m], bfr[n], acc[m][n], 0, 0, 0); \
    }

    const int nk = Ksl / BK;
    const int kg = lane >> 4;
    const int lr = lane & 15;
    int buf = 0;

    STAGE(0, 0);
    if constexpr (!AS32 && !BS32) {
        for (int kt = 0; kt < nk; ++kt) {
            if (kt + 1 < nk) {
                STAGE(buf ^ 1, kt + 1);
                asm volatile("s_waitcnt vmcnt(3)" ::: "memory");
            } else {
                asm volatile("s_waitcnt vmcnt(0)" ::: "memory");
            }
            __builtin_amdgcn_s_barrier();
            __builtin_amdgcn_sched_barrier(0);
            MFMA_BODY(buf);
            __builtin_amdgcn_s_barrier();
            buf ^= 1;
        }
    } else {
        __syncthreads();
        for (int kt = 0; kt < nk; ++kt) {
            if (kt + 1 < nk) STAGE(buf ^ 1, kt + 1);
            MFMA_BODY(buf);
            __syncthreads();
            buf ^= 1;
        }
    }
#undef STAGE
#undef MFMA_BODY

    const int ccol = lane & 15;
    const int crow = (lane >> 4) * 4;
#pragma unroll
    for (int n = 0; n < 2; ++n) {
        const int c = col0 + wcol + n * 16 + ccol;
        const float bv = bias ? bias[(long)az * sBiasb + c] : 0.f;
#pragma unroll
        for (int m = 0; m < 4; ++m) {
            const int rb = row0 + m * 16 + crow;
#pragma unroll
            for (int q = 0; q < 4; ++q) {
                const int r = rb + q;
                if (r >= M) continue;
                float v = acc[m][n][q] + bv;
                if (act == 1) v = 1.f / (1.f + expf(-v));
                else if (act == 2) v = tanhf(v);
                if (C)  C[(long)z * sCb + (long)r * ldc + c] = v;
                if (Cb) Cb[(long)z * sCbb + (long)r * ldcb + c] = (u16)bh(v);
            }
        }
    }
}

// ============ 128x128-tile fp32-in GEMM (Wnm setup) ============
__global__ __launch_bounds__(256)
void gemm128_f32(const float* __restrict__ A, int lda,
                 const float* __restrict__ Bm, int ldb,
                 float* __restrict__ C, long sCb, int ldc,
                 u16* __restrict__ Cb, int ldcb,
                 int M, int Nn, int K, int ksplit)
{
    __shared__ __align__(16) u16 lA[2][512][8];
    __shared__ __align__(16) u16 lB[2][512][8];

    const int ks = blockIdx.z;
    const int Ksl = K / ksplit;
    const int kbase = ks * Ksl;

    const int tid = threadIdx.x;
    const int lane = tid & 63;
    const int wave = tid >> 6;
    const int row0 = blockIdx.x * 128;
    const int col0 = blockIdx.y * 128;
    const int wrow = (wave >> 1) * 64;
    const int wcol = (wave & 1) * 64;

    const int rw = tid >> 1, hf = tid & 1;
    long ar = row0 + rw; if (ar >= M) ar = M - 1;
    long br = col0 + rw; if (br >= Nn) br = Nn - 1;

    f32x4 acc[4][4] = {};

#define STAGE128(b, kt) do {                                                  \
    const int k0_ = kbase + (kt) * BK;                                        \
    const float* p = A + ar * lda + k0_ + hf * 16;                            \
    *(s16x8*)&lA[b][(hf * 2) * 128 + rw][0] =                                 \
        pack8(*(const float4*)p, *(const float4*)(p + 4));                    \
    *(s16x8*)&lA[b][(hf * 2 + 1) * 128 + rw][0] =                             \
        pack8(*(const float4*)(p + 8), *(const float4*)(p + 12));             \
    const float* q = Bm + br * ldb + k0_ + hf * 16;                           \
    *(s16x8*)&lB[b][(hf * 2) * 128 + rw][0] =                                 \
        pack8(*(const float4*)q, *(const float4*)(q + 4));                    \
    *(s16x8*)&lB[b][(hf * 2 + 1) * 128 + rw][0] =                             \
        pack8(*(const float4*)(q + 8), *(const float4*)(q + 12));             \
} while (0)

    const int nk = Ksl / BK;
    STAGE128(0, 0);
    __syncthreads();
    int buf = 0;
    const int kg = lane >> 4;
    const int lr = lane & 15;
    for (int kt = 0; kt < nk; ++kt) {
        if (kt + 1 < nk) STAGE128(buf ^ 1, kt + 1);
        s16x8 af[4], bfr[4];
#pragma unroll
        for (int m = 0; m < 4; ++m)
            af[m] = *(const s16x8*)&lA[buf][kg * 128 + wrow + m * 16 + lr][0];
#pragma unroll
        for (int n = 0; n < 4; ++n)
            bfr[n] = *(const s16x8*)&lB[buf][kg * 128 + wcol + n * 16 + lr][0];
#pragma unroll
        for (int m = 0; m < 4; ++m)
#pragma unroll
            for (int n = 0; n < 4; ++n)
                acc[m][n] = __builtin_amdgcn_mfma_f32_16x16x32_bf16(af[m], bfr[n], acc[m][n], 0, 0, 0);
        __syncthreads();
        buf ^= 1;
    }
#undef STAGE128

    const int ccol = lane & 15;
    const int crow = (lane >> 4) * 4;
#pragma unroll
    for (int n = 0; n < 4; ++n) {
        const int c = col0 + wcol + n * 16 + ccol;
#pragma unroll
        for (int m = 0; m < 4; ++m) {
            const int rb = row0 + wrow + m * 16 + crow;
#pragma unroll
            for (int q = 0; q < 4; ++q) {
                const int r = rb + q;
                if (r >= M) continue;
                float v = acc[m][n][q];
                if (C)  C[(long)ks * sCb + (long)r * ldc + c] = v;
                if (Cb) Cb[(long)r * ldcb + c] = (u16)bh(v);
            }
        }
    }
}

// ============ fused gh-GEMM + GRU update + score partial (128x64, counted vmcnt) ============
__global__ __launch_bounds__(512)
void gh_gru(const u16* __restrict__ hb_in, const u16* __restrict__ Whh_b,
            const float* __restrict__ bhh, const u16* __restrict__ Gnm_b,
            const float* __restrict__ cbias,
            u16* __restrict__ hb_out,
            const float* __restrict__ Wa, float* __restrict__ gs_part, int tt)
{
    __shared__ __align__(16) u16 lA[2][1024][8];   // 32KB
    __shared__ __align__(16) u16 lB[2][1536][8];   // 48KB
    __shared__ float rowdot[128];

    const int f = blockIdx.x;
    const int ly = 2 * (f & 7) + ((f >> 3) & 1);   // 0..15 col-tile (XCD swizzle)
    const int lx = f >> 4;                          // 0..15 row-tile
    const int row0 = lx * 128;
    const int col0 = ly * 64;

    const int tid = threadIdx.x;
    const int lane = tid & 63;
    const int wave = tid >> 6;
    const int wr = wave >> 1;
    const int wc = wave & 1;

    long arow = row0 + (tid & 127); if (arow >= NROWS) arow = NROWS - 1;

    const u16* aP0 = hb_in + arow * SQ + (tid >> 7) * 8;
    const u16* aP1 = aP0 + 32;
    const u16* bP[3];
#pragma unroll
    for (int j = 0; j < 3; ++j) {
        const int s = tid + j * 512;
        const int bk16 = s / 192;
        const int grow = s - bk16 * 192;
        bP[j] = Whh_b + (long)((grow >> 6) * SQ + col0 + (grow & 63)) * SQ + bk16 * 8;
    }

    f32x4 acc[3][2][2] = {};

#define GSTAGE(b, kt) do {                                                    \
    const int k0_ = (kt) * 64;                                                \
    gload16(aP0 + k0_, &lA[b][tid][0]);                                       \
    gload16(aP1 + k0_, &lA[b][tid + 512][0]);                                 \
    _Pragma("unroll")                                                         \
    for (int j = 0; j < 3; ++j)                                               \
        gload16(bP[j] + k0_, &lB[b][tid + j * 512][0]);                       \
} while (0)

    GSTAGE(0, 0);
    int buf = 0;
    const int kg = lane >> 4;
    const int lr = lane & 15;
    for (int kt = 0; kt < 16; ++kt) {
        if (kt + 1 < 16) {
            GSTAGE(buf ^ 1, kt + 1);
            asm volatile("s_waitcnt vmcnt(5)" ::: "memory");
        } else {
            asm volatile("s_waitcnt vmcnt(0)" ::: "memory");
        }
        __builtin_amdgcn_s_barrier();
        __builtin_amdgcn_sched_barrier(0);
#pragma unroll
        for (int kk = 0; kk < 2; ++kk) {
            const int k16 = kk * 4 + kg;
            s16x8 af[2], bfr[3][2];
#pragma unroll
            for (int m = 0; m < 2; ++m)
                af[m] = *(const s16x8*)&lA[buf][k16 * 128 + wr * 32 + m * 16 + lr][0];
#pragma unroll
            for (int g = 0; g < 3; ++g)
#pragma unroll
                for (int n = 0; n < 2; ++n)
                    bfr[g][n] = *(const s16x8*)&lB[buf][k16 * 192 + g * 64 + wc * 32 + n * 16 + lr][0];
#pragma unroll
            for (int g = 0; g < 3; ++g)
#pragma unroll
                for (int m = 0; m < 2; ++m)
#pragma unroll
                    for (int n = 0; n < 2; ++n)
                        acc[g][m][n] = __builtin_amdgcn_mfma_f32_16x16x32_bf16(af[m], bfr[g][n], acc[g][m][n], 0, 0, 0);
        }
        __builtin_amdgcn_s_barrier();
        buf ^= 1;
    }
#undef GSTAGE

    if (tid < 128) rowdot[tid] = 0.f;
    __syncthreads();

    const int ccol = lane & 15;
    const int crow4 = (lane >> 4) * 4;
    int col2[2];
    float cbv[3][2], bhv[3][2];
#pragma unroll
    for (int n = 0; n < 2; ++n) {
        const int c = col0 + wc * 32 + n * 16 + ccol;
        col2[n] = c;
#pragma unroll
        for (int g = 0; g < 3; ++g) {
            cbv[g][n] = cbias[g * SQ + c];
            bhv[g][n] = bhh[g * SQ + c];
        }
    }

#pragma unroll
    for (int m = 0; m < 2; ++m) {
#pragma unroll
        for (int q = 0; q < 4; ++q) {
            const int row = row0 + wr * 32 + m * 16 + crow4 + q;
            const bool valid = (row < NROWS);
            float d = 0.f;
            if (valid) {
                const int e = row / BNN;
                const int rr = row - e * BNN;
                const int b_ = rr / 144;
                const int ni = (rr / 12) % 12;
                const int mi = rr % 12;
                const int bt = b_ * TQ + tt;
                const u16* gnp = Gnm_b + ((long)e * 96 + bt * 12 + ni) * 6144;
                const u16* gmp = Gnm_b + ((long)e * 96 + bt * 12 + mi) * 6144 + G3S;
                const float* wap = Wa + (long)e * SQ;
#pragma unroll
                for (int n = 0; n < 2; ++n) {
                    const int c = col2[n];
                    float gr  = acc[0][m][n][q] + bhv[0][n] + b2f(gnp[c]) + b2f(gmp[c]) + cbv[0][n];
                    float gz  = acc[1][m][n][q] + bhv[1][n] + b2f(gnp[SQ + c]) + b2f(gmp[SQ + c]) + cbv[1][n];
                    float ghn = acc[2][m][n][q] + bhv[2][n];
                    float gin = b2f(gnp[2 * SQ + c]) + b2f(gmp[2 * SQ + c]) + cbv[2][n];
                    float rg = sigmoidf(gr);
                    float zg = sigmoidf(gz);
                    float nn2 = tanhf(gin + rg * ghn);
                    float hp = b2f(hb_in[(long)row * SQ + c]);
                    float hn = (1.f - zg) * nn2 + zg * hp;
                    hb_out[(long)row * SQ + c] = (u16)bh(hn);
                    d += hn * wap[c];
                }
            }
            d += __shfl_xor(d, 1); d += __shfl_xor(d, 2);
            d += __shfl_xor(d, 4); d += __shfl_xor(d, 8);
            if (valid && ccol == 0)
                atomicAdd(&rowdot[wr * 32 + m * 16 + crow4 + q], d);
        }
    }
    __syncthreads();
    if (tid < 128) {
        const int row = row0 + tid;
        if (row < NROWS) gs_part[((long)tt * 2048 + row) * 16 + ly] = rowdot[tid];
    }
}

// ============ GRU step tt=0, elementwise ============
__global__ __launch_bounds__(256)
void gru0(const u16* __restrict__ Gnm_b, const float* __restrict__ cbias,
          const float* __restrict__ bhh,
          u16* __restrict__ hb_out,
          const float* __restrict__ Wa, const float* __restrict__ ba,
          float* __restrict__ gs)
{
    const int row = blockIdx.x;
    const int e = row / BNN;
    const int r = row % BNN;
    const int b_ = r / 144;
    const int ni = (r / 12) % 12;
    const int mi = r % 12;
    const int bt = b_ * TQ;

    const u16* gnp = Gnm_b + ((long)e * 96 + bt * 12 + ni) * 6144;
    const u16* gmp = Gnm_b + ((long)e * 96 + bt * 12 + mi) * 6144 + G3S;
    u16* hpb = hb_out + (long)row * SQ;

    const int s = threadIdx.x * 4;

    ushort4 nR = *(const ushort4*)(gnp + s);
    ushort4 nZ = *(const ushort4*)(gnp + SQ + s);
    ushort4 nN = *(const ushort4*)(gnp + 2 * SQ + s);
    ushort4 mR = *(const ushort4*)(gmp + s);
    ushort4 mZ = *(const ushort4*)(gmp + SQ + s);
    ushort4 mN = *(const ushort4*)(gmp + 2 * SQ + s);
    float4 cbR = *(const float4*)(cbias + s);
    float4 cbZ = *(const float4*)(cbias + SQ + s);
    float4 cbN = *(const float4*)(cbias + 2 * SQ + s);
    float4 bhR = *(const float4*)(bhh + s);
    float4 bhZ = *(const float4*)(bhh + SQ + s);
    float4 bhN = *(const float4*)(bhh + 2 * SQ + s);
    float4 wv  = *(const float4*)(Wa + (long)e * SQ + s);

    float4 hn4;
    float dot = 0.f;

#define GRU0_COMP(c, u)                                                       \
    {                                                                         \
        float rg = sigmoidf(b2f(nR.u) + b2f(mR.u) + cbR.c + bhR.c);           \
        float zg = sigmoidf(b2f(nZ.u) + b2f(mZ.u) + cbZ.c + bhZ.c);           \
        float nn = tanhf(b2f(nN.u) + b2f(mN.u) + cbN.c + rg * bhN.c);         \
        float hn = (1.f - zg) * nn;                                           \
        hn4.c = hn;                                                           \
        dot += hn * wv.c;                                                     \
    }
    GRU0_COMP(x, x) GRU0_COMP(y, y) GRU0_COMP(z, z) GRU0_COMP(w, w)
#undef GRU0_COMP

    ushort4 hb4;
    hb4.x = (u16)bh(hn4.x); hb4.y = (u16)bh(hn4.y);
    hb4.z = (u16)bh(hn4.z); hb4.w = (u16)bh(hn4.w);
    *(ushort4*)(hpb + s) = hb4;

    for (int off = 32; off > 0; off >>= 1) dot += __shfl_down(dot, off);
    __shared__ float red[4];
    if ((threadIdx.x & 63) == 0) red[threadIdx.x >> 6] = dot;
    __syncthreads();
    if (threadIdx.x == 0) {
        float tot = red[0] + red[1] + red[2] + red[3] + ba[e];
        gs[((bt * 12 + ni) * 12 + mi) * EQ + e] = sigmoidf(tot);
    }
}

// ---------- gs finalize for tt=1..3 (run once, before outputs) ----------
__global__ void gs_fin_all(const float* __restrict__ gs_part, const float* __restrict__ ba,
                           float* __restrict__ gs)
{
    int idx = blockIdx.x * 256 + threadIdx.x;
    if (idx >= 3 * 2048) return;
    const int tt = 1 + (idx >> 11);
    const int row = idx & 2047;
    if (row >= NROWS) return;
    float s = 0.f;
#pragma unroll
    for (int j = 0; j < 16; ++j) s += gs_part[((long)tt * 2048 + row) * 16 + j];
    const int e = row / BNN;
    const int rr = row - e * BNN;
    const int b_ = rr / 144;
    const int ni = (rr / 12) % 12;
    const int mi = rr % 12;
    const int bt = b_ * TQ + tt;
    gs[((bt * 12 + ni) * 12 + mi) * EQ + e] = sigmoidf(s + ba[e]);
}

// ---------- generic split-K reduce ----------
__global__ __launch_bounds__(256)
void reduce_k(const float* __restrict__ part, int ksplit, int mn, int Nn,
              const float* __restrict__ bias, long sBiasB, int act,
              float* __restrict__ Cf, long sCfB, int ldcf,
              u16* __restrict__ Cb, long sCbB, int ldcb)
{
    int i4 = blockIdx.x * 256 + threadIdx.x;
    int total4 = mn >> 2;
    if (i4 >= total4) return;
    int b = blockIdx.y;
    const float4* p4 = (const float4*)part;
    float4 s = make_float4(0.f, 0.f, 0.f, 0.f);
    for (int ks = 0; ks < ksplit; ++ks) {
        float4 v = p4[(long)(b * ksplit + ks) * total4 + i4];
        s.x += v.x; s.y += v.y; s.z += v.z; s.w += v.w;
    }
    int i = i4 << 2;
    int r = i / Nn, c = i % Nn;
    if (bias) {
        float4 bv = *(const float4*)(bias + (long)b * sBiasB + c);
        s.x += bv.x; s.y += bv.y; s.z += bv.z; s.w += bv.w;
    }
    if (act == 1) {
        s.x = sigmoidf(s.x); s.y = sigmoidf(s.y); s.z = sigmoidf(s.z); s.w = sigmoidf(s.w);
    } else if (act == 2) {
        s.x = tanhf(s.x); s.y = tanhf(s.y); s.z = tanhf(s.z); s.w = tanhf(s.w);
    }
    if (Cf) *(float4*)(Cf + (long)b * sCfB + (long)r * ldcf + c) = s;
    if (Cb) {
        ushort4 o;
        o.x = (u16)bh(s.x); o.y = (u16)bh(s.y); o.z = (u16)bh(s.z); o.w = (u16)bh(s.w);
        *(ushort4*)(Cb + (long)b * sCbB + (long)r * ldcb + c) = o;
    }
}

// ---------- fused rz split-K reduce + sigmoid + ahat + zbuf ----------
__global__ __launch_bounds__(256)
void rz_ahat_k(const float* __restrict__ part, const float* __restrict__ brz,
               const float* __restrict__ prop, u16* __restrict__ amat_b,
               float* __restrict__ zbuf)
{
    int i = blockIdx.x * 256 + threadIdx.x;
    int rrow = i >> 10, c = i & 1023;
    float sr = 0.f, sz = 0.f;
#pragma unroll
    for (int ks = 0; ks < 8; ++ks) {
        const float* p = part + (long)ks * 196608 + (long)rrow * 2048;
        sr += p[c]; sz += p[1024 + c];
    }
    float r = sigmoidf(sr + brz[c]);
    float z = sigmoidf(sz + brz[1024 + c]);
    amat_b[(long)rrow * 2048 + 1024 + c] = (u16)bh(r * prop[i]);
    zbuf[i] = z;
}

// ---------- fused hhat split-K reduce + tanh + prop update ----------
__global__ __launch_bounds__(256)
void hhat_prop_k(const float* __restrict__ part, const float* __restrict__ bh_,
                 const float* __restrict__ zbuf,
                 float* __restrict__ prop, u16* __restrict__ prop_b)
{
    int i = blockIdx.x * 256 + threadIdx.x;
    float s = 0.f;
#pragma unroll
    for (int ks = 0; ks < 8; ++ks) s += part[(long)ks * 98304 + i];
    float hhat = tanhf(s + bh_[i & 1023]);
    float z = zbuf[i];
    float v = (1.f - z) * prop[i] + z * hhat;
    prop[i] = v;
    prop_b[i] = (u16)bh(v);
}

// ---------- fused 3-buffer fp32 -> bf16 convert ----------
__global__ void cvt3_bf16_k(const float* __restrict__ s0, u16* __restrict__ d0, int n0,
                            const float* __restrict__ s1, u16* __restrict__ d1, int n1,
                            const float* __restrict__ s2, u16* __restrict__ d2, int n2)
{
    int i = blockIdx.x * 256 + threadIdx.x;
    const float* s; u16* d; int base;
    if (i < n0) { s = s0; d = d0; base = i; }
    else if (i < n0 + n1) { s = s1; d = d1; base = i - n0; }
    else if (i < n0 + n1 + n2) { s = s2; d = d2; base = i - n0 - n1; }
    else return;
    float4 v = ((const float4*)s)[base];
    ushort4 o;
    o.x = (u16)bh(v.x); o.y = (u16)bh(v.y); o.z = (u16)bh(v.z); o.w = (u16)bh(v.w);
    ((ushort4*)d)[base] = o;
}

__global__ __launch_bounds__(256)
void transpose_wc(const float* __restrict__ Wcomp, float* __restrict__ W1T, float* __restrict__ W2T)
{
    __shared__ float t1[32][33];
    __shared__ float t2[32][33];
    const int tx = threadIdx.x & 31;
    const int ty = threadIdx.x >> 5;
    const int d0 = blockIdx.x * 32;
    const int s0 = blockIdx.y * 32;
#pragma unroll
    for (int k = 0; k < 4; ++k) {
        int d = d0 + ty + k * 8;
        t1[ty + k * 8][tx] = Wcomp[(long)d * 2048 + s0 + tx];
        t2[ty + k * 8][tx] = Wcomp[(long)d * 2048 + 1024 + s0 + tx];
    }
    __syncthreads();
#pragma unroll
    for (int k = 0; k < 4; ++k) {
        int s = s0 + ty + k * 8;
        W1T[(long)s * 1024 + d0 + tx] = t1[tx][ty + k * 8];
        W2T[(long)s * 1024 + d0 + tx] = t2[tx][ty + k * 8];
    }
}

__global__ void pack_rz(const float* __restrict__ Wr, const float* __restrict__ Wz,
                        const float* __restrict__ br, const float* __restrict__ bz,
                        u16* __restrict__ Wrz, float* __restrict__ brz)
{
    int i4 = blockIdx.x * 256 + threadIdx.x;
    if (i4 < 512) {
        int c = i4 * 4;
        float4 b = (c < 1024) ? *(const float4*)(br + c) : *(const float4*)(bz + c - 1024);
        *(float4*)(brz + c) = b;
    }
    if (i4 >= 1048576) return;
    int i = i4 * 4;
    int j = i >> 11;
    int c = i & 2047;
    float4 v = (j < 1024) ? *(const float4*)(Wr + (long)j * 2048 + c)
                          : *(const float4*)(Wz + (long)(j - 1024) * 2048 + c);
    ushort4 o;
    o.x = (u16)bh(v.x); o.y = (u16)bh(v.y); o.z = (u16)bh(v.z); o.w = (u16)bh(v.w);
    *(ushort4*)(Wrz + i) = o;
}

__global__ void cbias_k(const float* __restrict__ Wih, const float* __restrict__ bih,
                        const float* __restrict__ bcomp, float* __restrict__ cbias)
{
    int g = blockIdx.x * blockDim.x + threadIdx.x;
    if (g >= G3S) return;
    const float* w = Wih + (long)g * SQ;
    float s = 0.f;
    for (int k = 0; k < SQ; k += 4) {
        float4 wv = *(const float4*)(w + k);
        float4 bv = *(const float4*)(bcomp + k);
        s += wv.x * bv.x + wv.y * bv.y + wv.z * bv.z + wv.w * bv.w;
    }
    cbias[g] = s + bih[g];
}

// ---------------- merged + amat fused (+ inline gs finalize for tt != 0) ----------------
__global__ __launch_bounds__(256)
void merged_amat_k(const float* __restrict__ gs, const float* __restrict__ gs_part,
                   const float* __restrict__ ba,
                   const u16* __restrict__ msgs_b,
                   const float* __restrict__ prop, u16* __restrict__ amat_b)
{
    const int bn = blockIdx.x;   // bt*12+n
    const int bt = bn / 12;
    const int n = bn - bt * 12;
    const int b_ = bt / TQ;
    const int tt = bt - b_ * TQ;
    __shared__ float g[84];
    if (threadIdx.x < 84) {
        const int m = threadIdx.x / 7;
        const int e = threadIdx.x - m * 7;
        float val;
        if (tt == 0) {
            val = gs[bn * 84 + threadIdx.x];
        } else {
            const int row = e * BNN + b_ * 144 + n * 12 + m;
            float s = 0.f;
#pragma unroll
            for (int j = 0; j < 16; ++j) s += gs_part[((long)tt * 2048 + row) * 16 + j];
            val = sigmoidf(s + ba[e]);
        }
        g[threadIdx.x] = val;
    }
    __syncthreads();
    const int s = threadIdx.x * 4;
    float4 acc = make_float4(0.f, 0.f, 0.f, 0.f);
    for (int j = 0; j < 84; ++j) {
        const ushort4 mv = *(const ushort4*)(msgs_b + ((long)(bt * 84 + j)) * SQ + s);
        float gj = g[j];
        acc.x += gj * b2f(mv.x);
        acc.y += gj * b2f(mv.y);
        acc.z += gj * b2f(mv.z);
        acc.w += gj * b2f(mv.w);
    }
    ushort4 o;
    o.x = (u16)bh(acc.x); o.y = (u16)bh(acc.y); o.z = (u16)bh(acc.z); o.w = (u16)bh(acc.w);
    *(ushort4*)(amat_b + (long)bn * 2048 + s) = o;
    float4 pv = *(const float4*)(prop + (long)bn * SQ + s);
    ushort4 o2;
    o2.x = (u16)bh(pv.x); o2.y = (u16)bh(pv.y); o2.z = (u16)bh(pv.z); o2.w = (u16)bh(pv.w);
    *(ushort4*)(amat_b + (long)bn * 2048 + 1024 + s) = o2;
}

// ---------------- final outputs ----------------
__global__ __launch_bounds__(256)
void outputs_k(const float* __restrict__ gs, float* __restrict__ out)
{
    __shared__ float s_act[672];
    __shared__ float s_asum[96];
    int tid = threadIdx.x;
    for (int idx = tid; idx < 672; idx += 256) {
        int bn = idx / 7, e = idx % 7;
        float sum = 0.f;
        for (int m = 0; m < 12; ++m) {
            float g0 = gs[bn * 84 + m * 7];
            sum += (1.f - g0) * gs[bn * 84 + m * 7 + e];
        }
        s_act[idx] = sum;
        out[idx] = sum;
    }
    for (int idx = tid; idx < 96; idx += 256) {
        float a = 0.f;
        for (int m = 0; m < 12; ++m) a += 1.f - gs[idx * 84 + m * 7];
        s_asum[idx] = a;
    }
    for (int idx = tid; idx < 1152; idx += 256) {
        int bn = idx / 12, m = idx % 12;
        out[720 + idx] = 1.f - gs[bn * 84 + m * 7];
    }
    __syncthreads();
    if (tid < 8) {
        float tmp[6];
        float mx = -1e30f;
        for (int e = 1; e < 7; ++e) {
            float sum = 0.f;
            for (int n = 0; n < 12; ++n) {
                int bn = tid * 12 + n;
                sum += s_act[bn * 7 + e] * s_asum[bn];
            }
            tmp[e - 1] = sum;
            mx = fmaxf(mx, sum);
        }
        float den = 0.f;
        for (int e = 0; e < 6; ++e) { tmp[e] = expf(tmp[e] - mx); den += tmp[e]; }
        for (int e = 0; e < 6; ++e) out[672 + tid * 6 + e] = tmp[e] / den;
    }
}

// ---------------- host ----------------
template<int AS32, int BS32>
static void launch_gemm(const void* A, long sAb, int lda,
                        const void* B, long sBb, int ldb,
                        const float* bias, long sBiasb,
                        float* C, long sCb, int ldc,
                        u16* Cb, long sCbb, int ldcb,
                        int M, int Nn, int K, int act, int batch, int ksplit,
                        hipStream_t stream)
{
    dim3 grid((M + 63) / 64, (Nn + 127) / 128, batch * ksplit);
    gemm_mfma<AS32, BS32><<<grid, dim3(256), 0, stream>>>(
        A, sAb, lda, B, sBb, ldb, bias, sBiasb, C, sCb, ldc, Cb, sCbb, ldcb,
        M, Nn, K, act, ksplit);
}

extern "C" void kernel_launch(void* const* d_in, const int* in_sizes, int n_in,
                              void* d_out, int out_size, void* d_ws, size_t ws_size,
                              hipStream_t stream)
{
    const float* pose  = (const float*)d_in[0];
    const float* Wc    = (const float*)d_in[5];
    const float* bc    = (const float*)d_in[6];
    const float* We    = (const float*)d_in[7];
    const float* be    = (const float*)d_in[8];
    const float* Wcomp = (const float*)d_in[9];
    const float* bcomp = (const float*)d_in[10];
    const float* Wr    = (const float*)d_in[11];
    const float* br    = (const float*)d_in[12];
    const float* Wz    = (const float*)d_in[13];
    const float* bz    = (const float*)d_in[14];
    const float* Wh    = (const float*)d_in[15];
    const float* bh_   = (const float*)d_in[16];
    const float* Wih   = (const float*)d_in[17];
    const float* Whh   = (const float*)d_in[18];
    const float* bih   = (const float*)d_in[19];
    const float* bhh   = (const float*)d_in[20];
    const float* Wa    = (const float*)d_in[21];
    const float* ba    = (const float*)d_in[22];

    float* ws = (float*)d_ws;
    // fp32 region
    float* prop    = ws;                    // 98304
    float* cbias   = prop + 98304;          // 3072
    float* scratch = cbias + 3072;          // 8257536
    float* gs      = scratch + 8257536;     // 8064
    float* zbuf    = gs + 8064;             // 98304
    float* brz     = zbuf + 98304;          // 2048
    float* gs_part = brz + 2048;            // 131072 (4 x 2048 x 16)
    float* fend    = gs_part + 131072;
    // bf16 region
    u16* Whh_b  = (u16*)fend;               // 3145728
    u16* Wnm_b  = Whh_b + 3145728;          // 6291456
    u16* Wrz_b  = Wnm_b + 6291456;          // 4194304
    u16* Gnm_b  = Wrz_b + 4194304;          // 4128768
    u16* msgs_b = Gnm_b + 4128768;          // 688128
    u16* h_b0   = msgs_b + 688128;          // 2064384
    u16* h_b1   = h_b0 + 2064384;           // 2064384
    u16* prop_b = h_b1 + 2064384;           // 98304
    u16* amat_b = prop_b + 98304;           // 196608
    u16* pose_b = amat_b + 196608;          // 2534400
    u16* Wc_b   = pose_b + 2534400;         // 27033600

    float* W1T = scratch;                   // transient
    float* W2T = scratch + 1048576;         // transient

    // ---- once per call ----
    hipLaunchKernelGGL(cvt3_bf16_k, dim3(31947), dim3(256), 0, stream,
                       Whh, Whh_b, 786432, pose, pose_b, 633600, Wc, Wc_b, 6758400);
    hipLaunchKernelGGL(cbias_k, dim3(12), dim3(256), 0, stream, Wih, bih, bcomp, cbias);
    hipLaunchKernelGGL(transpose_wc, dim3(32, 32), dim3(256), 0, stream, Wcomp, W1T, W2T);
    hipLaunchKernelGGL(pack_rz, dim3(4096), dim3(256), 0, stream, Wr, Wz, br, bz, Wrz_b, brz);
    gemm128_f32<<<dim3(24, 8, 1), dim3(256), 0, stream>>>(
        Wih, SQ, W1T, SQ, nullptr, 0, SQ, Wnm_b, SQ, G3S, SQ, SQ, 1);
    gemm128_f32<<<dim3(24, 8, 1), dim3(256), 0, stream>>>(
        Wih, SQ, W2T, SQ, nullptr, 0, SQ, Wnm_b + (long)G3S * SQ, SQ, G3S, SQ, SQ, 1);
    // prop = pose @ Wc^T + bc : bf16 operands, ksplit=55
    launch_gemm<0, 0>(pose_b, 0, DIN, Wc_b, 0, DIN, nullptr, 0,
                      scratch, 98304, SQ, nullptr, 0, 0, 96, SQ, DIN, 0, 1, 55, stream);
    hipLaunchKernelGGL(reduce_k, dim3(96, 1), dim3(256), 0, stream,
                       scratch, 55, 98304, SQ, bc, 0L, 0,
                       prop, 0L, SQ, prop_b, 0L, SQ);

    for (int t = 0; t <= TSQ; ++t) {
        // msgs[bt,n,e,s] = prop @ We[e]^T + be[e] : batch 7, ksplit 4
        launch_gemm<0, 1>(prop_b, 0, SQ, We, (long)SQ * SQ, SQ, nullptr, 0,
                          scratch, 98304, SQ, nullptr, 0, 0, 96, SQ, SQ, 0, EQ, 4, stream);
        hipLaunchKernelGGL(reduce_k, dim3(96, EQ), dim3(256), 0, stream,
                           scratch, 4, 98304, SQ, be, (long)SQ, 0,
                           (float*)nullptr, 0L, 0, msgs_b, (long)SQ, EQ * SQ);
        // Gnm = msgs_e @ Wnm^T : batch 7, direct bf16 write
        launch_gemm<0, 0>(msgs_b, SQ, EQ * SQ, Wnm_b, 0, SQ, nullptr, 0,
                          nullptr, 0, 0, Gnm_b, 589824, 6 * SQ, 96, 6 * SQ, SQ, 0, EQ, 1, stream);
        // GRU scan: tt=0 elementwise, then 3 fused GEMM steps (bf16-carried h)
        hipLaunchKernelGGL(gru0, dim3(NROWS), dim3(256), 0, stream,
                           Gnm_b, cbias, bhh, h_b0, Wa, ba, gs);
        for (int tt = 1; tt < TQ; ++tt) {
            const u16* hin = (tt & 1) ? h_b0 : h_b1;
            u16* hout = (tt & 1) ? h_b1 : h_b0;
            hipLaunchKernelGGL(gh_gru, dim3(256), dim3(512), 0, stream,
                               hin, Whh_b, bhh, Gnm_b, cbias, hout, Wa, gs_part, tt);
        }
        if (t < TSQ) {
            // merged+amat with inline gs finalize (reads gs_part for tt != 0)
            hipLaunchKernelGGL(merged_amat_k, dim3(96), dim3(256), 0, stream,
                               gs, gs_part, ba, msgs_b, prop, amat_b);
            // rz partials : ksplit=8
            launch_gemm<0, 0>(amat_b, 0, 2 * SQ, Wrz_b, 0, 2 * SQ, nullptr, 0,
                              scratch, 196608, 2 * SQ, nullptr, 0, 0, 96, 2 * SQ, 2 * SQ, 0, 1, 8, stream);
            hipLaunchKernelGGL(rz_ahat_k, dim3(384), dim3(256), 0, stream,
                               scratch, brz, prop, amat_b, zbuf);
            // hhat partials : ksplit=8
            launch_gemm<0, 1>(amat_b, 0, 2 * SQ, Wh, 0, 2 * SQ, nullptr, 0,
                              scratch, 98304, SQ, nullptr, 0, 0, 96, SQ, 2 * SQ, 0, 1, 8, stream);
            hipLaunchKernelGGL(hhat_prop_k, dim3(384), dim3(256), 0, stream,
                               scratch, bh_, zbuf, prop, prop_b);
        }
    }

    // finalize gs for tt=1..3 of the LAST t, then outputs
    hipLaunchKernelGGL(gs_fin_all, dim3(24), dim3(256), 0, stream, gs_part, ba, gs);
    hipLaunchKernelGGL(outputs_k, dim3(1), dim3(256), 0, stream, gs, (float*)d_out);
}

// Round 14
// 1118.323 us; speedup vs baseline: 2.6845x; 1.0006x over previous
//
#include <hip/hip_runtime.h>
#include <math.h>

// Problem constants
#define NQ 12
#define EQ 7
#define SQ 1024
#define TSQ 3
#define DIN 26400
#define BQ 2
#define TQ 4
#define BT 8          // B*T
#define BNN 288       // B*N*N
#define NROWS 2016    // E*BNN
#define G3S 3072      // 3*S
#define BK 32

typedef unsigned short u16;
typedef float f32x4 __attribute__((ext_vector_type(4)));
typedef short s16x8 __attribute__((ext_vector_type(8)));

__device__ __forceinline__ short bh(float f) {
    unsigned u = __float_as_uint(f);
    return (short)((u + 0x8000u) >> 16);
}
__device__ __forceinline__ float b2f(u16 u) {
    return __uint_as_float((unsigned)u << 16);
}
__device__ __forceinline__ s16x8 pack8(float4 a, float4 b) {
    s16x8 r;
    r[0] = bh(a.x); r[1] = bh(a.y); r[2] = bh(a.z); r[3] = bh(a.w);
    r[4] = bh(b.x); r[5] = bh(b.y); r[6] = bh(b.z); r[7] = bh(b.w);
    return r;
}
__device__ __forceinline__ void gload16(const void* g, void* l) {
    __builtin_amdgcn_global_load_lds(
        (const __attribute__((address_space(1))) unsigned*)g,
        (__attribute__((address_space(3))) unsigned*)l, 16, 0, 0);
}
__device__ inline float sigmoidf(float x) { return 1.f / (1.f + expf(-x)); }

// ================= bf16 MFMA GEMM, 64x128 tile: C = A(MxK) * B(NxK)^T =================
template<int AS32, int BS32>
__global__ __launch_bounds__(256)
void gemm_mfma(const void* __restrict__ Ap, long sAb, int lda,
               const void* __restrict__ Bp, long sBb, int ldb,
               const float* __restrict__ bias, long sBiasb,
               float* __restrict__ C, long sCb, int ldc,
               u16* __restrict__ Cb, long sCbb, int ldcb,
               int M, int Nn, int K, int act, int ksplit)
{
    __shared__ __align__(16) u16 lA[2][256][8];
    __shared__ __align__(16) u16 lB[2][512][8];

    const int z = blockIdx.z;
    const int az = z / ksplit;
    const int ks = z - az * ksplit;
    const int Ksl = K / ksplit;
    const int kbase = ks * Ksl;

    const char* Abase = (const char*)Ap + (long)az * sAb * (AS32 ? 4 : 2);
    const char* Bbase = (const char*)Bp + (long)az * sBb * (BS32 ? 4 : 2);

    const int tid = threadIdx.x;
    const int lane = tid & 63;
    const int wave = tid >> 6;
    const int row0 = blockIdx.x * 64;
    const int col0 = blockIdx.y * 128;
    const int wcol = wave * 32;

    const int akg = tid >> 6;
    long arow = row0 + (tid & 63); if (arow >= M) arow = M - 1;
    const int bkg0 = tid >> 7;
    const int s1 = tid + 256;
    const int bkg1 = s1 >> 7;
    long brow0 = col0 + (tid & 127); if (brow0 >= Nn) brow0 = Nn - 1;
    long brow1 = col0 + (s1 & 127);  if (brow1 >= Nn) brow1 = Nn - 1;

    const int arw32 = tid >> 2, akg32 = tid & 3;
    long ar32 = row0 + arw32; if (ar32 >= M) ar32 = M - 1;
    const int brw32 = tid >> 1, bh32 = tid & 1;
    long br32 = col0 + brw32; if (br32 >= Nn) br32 = Nn - 1;

    f32x4 acc[4][2] = {};

#define STAGE(b, kt) do {                                                     \
    const int k0_ = kbase + (kt) * BK;                                        \
    if constexpr (AS32) {                                                     \
        const float* A32 = (const float*)Abase;                               \
        const float* p0 = A32 + ar32 * lda + k0_ + akg32 * 8;                 \
        *(s16x8*)&lA[b][akg32 * 64 + arw32][0] =                              \
            pack8(*(const float4*)p0, *(const float4*)(p0 + 4));              \
    } else {                                                                  \
        const u16* A16 = (const u16*)Abase;                                   \
        gload16(A16 + arow * lda + k0_ + akg * 8, &lA[b][tid][0]);            \
    }                                                                         \
    if constexpr (BS32) {                                                     \
        const float* B32 = (const float*)Bbase;                               \
        const float* q0 = B32 + br32 * ldb + k0_ + bh32 * 16;                 \
        *(s16x8*)&lB[b][(bh32 * 2) * 128 + brw32][0] =                        \
            pack8(*(const float4*)q0, *(const float4*)(q0 + 4));              \
        *(s16x8*)&lB[b][(bh32 * 2 + 1) * 128 + brw32][0] =                    \
            pack8(*(const float4*)(q0 + 8), *(const float4*)(q0 + 12));       \
    } else {                                                                  \
        const u16* B16 = (const u16*)Bbase;                                   \
        gload16(B16 + brow0 * ldb + k0_ + bkg0 * 8, &lB[b][tid][0]);          \
        gload16(B16 + brow1 * ldb + k0_ + bkg1 * 8, &lB[b][s1][0]);           \
    }                                                                         \
} while (0)

#define MFMA_BODY(bufi)                                                       \
    {                                                                         \
        s16x8 af[4], bfr[2];                                                  \
        _Pragma("unroll")                                                     \
        for (int m = 0; m < 4; ++m)                                           \
            af[m] = *(const s16x8*)&lA[bufi][kg * 64 + m * 16 + lr][0];       \
        _Pragma("unroll")                                                     \
        for (int n = 0; n < 2; ++n)                                           \
            bfr[n] = *(const s16x8*)&lB[bufi][kg * 128 + wcol + n * 16 + lr][0]; \
        _Pragma("unroll")                                                     \
        for (int m = 0; m < 4; ++m)                                           \
            _Pragma("unroll")                                                 \
            for (int n = 0; n < 2; ++n)                                       \
                acc[m][n] = __builtin_amdgcn_mfma_f32_16x16x32_bf16(af[m], bfr[n], acc[m][n], 0, 0, 0); \
    }

    const int nk = Ksl / BK;
    const int kg = lane >> 4;
    const int lr = lane & 15;
    int buf = 0;

    STAGE(0, 0);
    if constexpr (!AS32 && !BS32) {
        for (int kt = 0; kt < nk; ++kt) {
            if (kt + 1 < nk) {
                STAGE(buf ^ 1, kt + 1);
                asm volatile("s_waitcnt vmcnt(3)" ::: "memory");
            } else {
                asm volatile("s_waitcnt vmcnt(0)" ::: "memory");
            }
            __builtin_amdgcn_s_barrier();
            __builtin_amdgcn_sched_barrier(0);
            MFMA_BODY(buf);
            __builtin_amdgcn_s_barrier();
            buf ^= 1;
        }
    } else {
        __syncthreads();
        for (int kt = 0; kt < nk; ++kt) {
            if (kt + 1 < nk) STAGE(buf ^ 1, kt + 1);
            MFMA_BODY(buf);
            __syncthreads();
            buf ^= 1;
        }
    }
#undef STAGE
#undef MFMA_BODY

    const int ccol = lane & 15;
    const int crow = (lane >> 4) * 4;
#pragma unroll
    for (int n = 0; n < 2; ++n) {
        const int c = col0 + wcol + n * 16 + ccol;
        const float bv = bias ? bias[(long)az * sBiasb + c] : 0.f;
#pragma unroll
        for (int m = 0; m < 4; ++m) {
            const int rb = row0 + m * 16 + crow;
#pragma unroll
            for (int q = 0; q < 4; ++q) {
                const int r = rb + q;
                if (r >= M) continue;
                float v = acc[m][n][q] + bv;
                if (act == 1) v = 1.f / (1.f + expf(-v));
                else if (act == 2) v = tanhf(v);
                if (C)  C[(long)z * sCb + (long)r * ldc + c] = v;
                if (Cb) Cb[(long)z * sCbb + (long)r * ldcb + c] = (u16)bh(v);
            }
        }
    }
}

// ============ 128x128-tile fp32-in GEMM (Wnm setup) ============
__global__ __launch_bounds__(256)
void gemm128_f32(const float* __restrict__ A, int lda,
                 const float* __restrict__ Bm, int ldb,
                 float* __restrict__ C, long sCb, int ldc,
                 u16* __restrict__ Cb, int ldcb,
                 int M, int Nn, int K, int ksplit)
{
    __shared__ __align__(16) u16 lA[2][512][8];
    __shared__ __align__(16) u16 lB[2][512][8];

    const int ks = blockIdx.z;
    const int Ksl = K / ksplit;
    const int kbase = ks * Ksl;

    const int tid = threadIdx.x;
    const int lane = tid & 63;
    const int wave = tid >> 6;
    const int row0 = blockIdx.x * 128;
    const int col0 = blockIdx.y * 128;
    const int wrow = (wave >> 1) * 64;
    const int wcol = (wave & 1) * 64;

    const int rw = tid >> 1, hf = tid & 1;
    long ar = row0 + rw; if (ar >= M) ar = M - 1;
    long br = col0 + rw; if (br >= Nn) br = Nn - 1;

    f32x4 acc[4][4] = {};

#define STAGE128(b, kt) do {                                                  \
    const int k0_ = kbase + (kt) * BK;                                        \
    const float* p = A + ar * lda + k0_ + hf * 16;                            \
    *(s16x8*)&lA[b][(hf * 2) * 128 + rw][0] =                                 \
        pack8(*(const float4*)p, *(const float4*)(p + 4));                    \
    *(s16x8*)&lA[b][(hf * 2 + 1) * 128 + rw][0] =                             \
        pack8(*(const float4*)(p + 8), *(const float4*)(p + 12));             \
    const float* q = Bm + br * ldb + k0_ + hf * 16;                           \
    *(s16x8*)&lB[b][(hf * 2) * 128 + rw][0] =                                 \
        pack8(*(const float4*)q, *(const float4*)(q + 4));                    \
    *(s16x8*)&lB[b][(hf * 2 + 1) * 128 + rw][0] =                             \
        pack8(*(const float4*)(q + 8), *(const float4*)(q + 12));             \
} while (0)

    const int nk = Ksl / BK;
    STAGE128(0, 0);
    __syncthreads();
    int buf = 0;
    const int kg = lane >> 4;
    const int lr = lane & 15;
    for (int kt = 0; kt < nk; ++kt) {
        if (kt + 1 < nk) STAGE128(buf ^ 1, kt + 1);
        s16x8 af[4], bfr[4];
#pragma unroll
        for (int m = 0; m < 4; ++m)
            af[m] = *(const s16x8*)&lA[buf][kg * 128 + wrow + m * 16 + lr][0];
#pragma unroll
        for (int n = 0; n < 4; ++n)
            bfr[n] = *(const s16x8*)&lB[buf][kg * 128 + wcol + n * 16 + lr][0];
#pragma unroll
        for (int m = 0; m < 4; ++m)
#pragma unroll
            for (int n = 0; n < 4; ++n)
                acc[m][n] = __builtin_amdgcn_mfma_f32_16x16x32_bf16(af[m], bfr[n], acc[m][n], 0, 0, 0);
        __syncthreads();
        buf ^= 1;
    }
#undef STAGE128

    const int ccol = lane & 15;
    const int crow = (lane >> 4) * 4;
#pragma unroll
    for (int n = 0; n < 4; ++n) {
        const int c = col0 + wcol + n * 16 + ccol;
#pragma unroll
        for (int m = 0; m < 4; ++m) {
            const int rb = row0 + wrow + m * 16 + crow;
#pragma unroll
            for (int q = 0; q < 4; ++q) {
                const int r = rb + q;
                if (r >= M) continue;
                float v = acc[m][n][q];
                if (C)  C[(long)ks * sCb + (long)r * ldc + c] = v;
                if (Cb) Cb[(long)r * ldcb + c] = (u16)bh(v);
            }
        }
    }
}

// ============ fused gh-GEMM + GRU update + score partial (128x64, counted vmcnt) ============
__global__ __launch_bounds__(512)
void gh_gru(const u16* __restrict__ hb_in, const u16* __restrict__ Whh_b,
            const float* __restrict__ bhh, const u16* __restrict__ Gnm_b,
            const float* __restrict__ cbias,
            u16* __restrict__ hb_out,
            const float* __restrict__ Wa, float* __restrict__ gs_part, int tt)
{
    __shared__ __align__(16) u16 lA[2][1024][8];   // 32KB
    __shared__ __align__(16) u16 lB[2][1536][8];   // 48KB
    __shared__ float rowdot[128];

    const int f = blockIdx.x;
    const int ly = 2 * (f & 7) + ((f >> 3) & 1);   // 0..15 col-tile (XCD swizzle)
    const int lx = f >> 4;                          // 0..15 row-tile
    const int row0 = lx * 128;
    const int col0 = ly * 64;

    const int tid = threadIdx.x;
    const int lane = tid & 63;
    const int wave = tid >> 6;
    const int wr = wave >> 1;
    const int wc = wave & 1;

    long arow = row0 + (tid & 127); if (arow >= NROWS) arow = NROWS - 1;

    const u16* aP0 = hb_in + arow * SQ + (tid >> 7) * 8;
    const u16* aP1 = aP0 + 32;
    const u16* bP[3];
#pragma unroll
    for (int j = 0; j < 3; ++j) {
        const int s = tid + j * 512;
        const int bk16 = s / 192;
        const int grow = s - bk16 * 192;
        bP[j] = Whh_b + (long)((grow >> 6) * SQ + col0 + (grow & 63)) * SQ + bk16 * 8;
    }

    f32x4 acc[3][2][2] = {};

#define GSTAGE(b, kt) do {                                                    \
    const int k0_ = (kt) * 64;                                                \
    gload16(aP0 + k0_, &lA[b][tid][0]);                                       \
    gload16(aP1 + k0_, &lA[b][tid + 512][0]);                                 \
    _Pragma("unroll")                                                         \
    for (int j = 0; j < 3; ++j)                                               \
        gload16(bP[j] + k0_, &lB[b][tid + j * 512][0]);                       \
} while (0)

    GSTAGE(0, 0);
    int buf = 0;
    const int kg = lane >> 4;
    const int lr = lane & 15;
    for (int kt = 0; kt < 16; ++kt) {
        if (kt + 1 < 16) {
            GSTAGE(buf ^ 1, kt + 1);
            asm volatile("s_waitcnt vmcnt(5)" ::: "memory");
        } else {
            asm volatile("s_waitcnt vmcnt(0)" ::: "memory");
        }
        __builtin_amdgcn_s_barrier();
        __builtin_amdgcn_sched_barrier(0);
#pragma unroll
        for (int kk = 0; kk < 2; ++kk) {
            const int k16 = kk * 4 + kg;
            s16x8 af[2], bfr[3][2];
#pragma unroll
            for (int m = 0; m < 2; ++m)
                af[m] = *(const s16x8*)&lA[buf][k16 * 128 + wr * 32 + m * 16 + lr][0];
#pragma unroll
            for (int g = 0; g < 3; ++g)
#pragma unroll
                for (int n = 0; n < 2; ++n)
                    bfr[g][n] = *(const s16x8*)&lB[buf][k16 * 192 + g * 64 + wc * 32 + n * 16 + lr][0];
#pragma unroll
            for (int g = 0; g < 3; ++g)
#pragma unroll
                for (int m = 0; m < 2; ++m)
#pragma unroll
                    for (int n = 0; n < 2; ++n)
                        acc[g][m][n] = __builtin_amdgcn_mfma_f32_16x16x32_bf16(af[m], bfr[g][n], acc[g][m][n], 0, 0, 0);
        }
        __builtin_amdgcn_s_barrier();
        buf ^= 1;
    }
#undef GSTAGE

    if (tid < 128) rowdot[tid] = 0.f;
    __syncthreads();

    const int ccol = lane & 15;
    const int crow4 = (lane >> 4) * 4;
    int col2[2];
    float cbv[3][2], bhv[3][2];
#pragma unroll
    for (int n = 0; n < 2; ++n) {
        const int c = col0 + wc * 32 + n * 16 + ccol;
        col2[n] = c;
#pragma unroll
        for (int g = 0; g < 3; ++g) {
            cbv[g][n] = cbias[g * SQ + c];
            bhv[g][n] = bhh[g * SQ + c];
        }
    }

#pragma unroll
    for (int m = 0; m < 2; ++m) {
#pragma unroll
        for (int q = 0; q < 4; ++q) {
            const int row = row0 + wr * 32 + m * 16 + crow4 + q;
            const bool valid = (row < NROWS);
            float d = 0.f;
            if (valid) {
                const int e = row / BNN;
                const int rr = row - e * BNN;
                const int b_ = rr / 144;
                const int ni = (rr / 12) % 12;
                const int mi = rr % 12;
                const int bt = b_ * TQ + tt;
                const u16* gnp = Gnm_b + ((long)e * 96 + bt * 12 + ni) * 6144;
                const u16* gmp = Gnm_b + ((long)e * 96 + bt * 12 + mi) * 6144 + G3S;
                const float* wap = Wa + (long)e * SQ;
#pragma unroll
                for (int n = 0; n < 2; ++n) {
                    const int c = col2[n];
                    float gr  = acc[0][m][n][q] + bhv[0][n] + b2f(gnp[c]) + b2f(gmp[c]) + cbv[0][n];
                    float gz  = acc[1][m][n][q] + bhv[1][n] + b2f(gnp[SQ + c]) + b2f(gmp[SQ + c]) + cbv[1][n];
                    float ghn = acc[2][m][n][q] + bhv[2][n];
                    float gin = b2f(gnp[2 * SQ + c]) + b2f(gmp[2 * SQ + c]) + cbv[2][n];
                    float rg = sigmoidf(gr);
                    float zg = sigmoidf(gz);
                    float nn2 = tanhf(gin + rg * ghn);
                    float hp = b2f(hb_in[(long)row * SQ + c]);
                    float hn = (1.f - zg) * nn2 + zg * hp;
                    hb_out[(long)row * SQ + c] = (u16)bh(hn);
                    d += hn * wap[c];
                }
            }
            d += __shfl_xor(d, 1); d += __shfl_xor(d, 2);
            d += __shfl_xor(d, 4); d += __shfl_xor(d, 8);
            if (valid && ccol == 0)
                atomicAdd(&rowdot[wr * 32 + m * 16 + crow4 + q], d);
        }
    }
    __syncthreads();
    if (tid < 128) {
        const int row = row0 + tid;
        if (row < NROWS) gs_part[((long)tt * 2048 + row) * 16 + ly] = rowdot[tid];
    }
}

// ============ GRU step tt=0, elementwise ============
__global__ __launch_bounds__(256)
void gru0(const u16* __restrict__ Gnm_b, const float* __restrict__ cbias,
          const float* __restrict__ bhh,
          u16* __restrict__ hb_out,
          const float* __restrict__ Wa, const float* __restrict__ ba,
          float* __restrict__ gs)
{
    const int row = blockIdx.x;
    const int e = row / BNN;
    const int r = row % BNN;
    const int b_ = r / 144;
    const int ni = (r / 12) % 12;
    const int mi = r % 12;
    const int bt = b_ * TQ;

    const u16* gnp = Gnm_b + ((long)e * 96 + bt * 12 + ni) * 6144;
    const u16* gmp = Gnm_b + ((long)e * 96 + bt * 12 + mi) * 6144 + G3S;
    u16* hpb = hb_out + (long)row * SQ;

    const int s = threadIdx.x * 4;

    ushort4 nR = *(const ushort4*)(gnp + s);
    ushort4 nZ = *(const ushort4*)(gnp + SQ + s);
    ushort4 nN = *(const ushort4*)(gnp + 2 * SQ + s);
    ushort4 mR = *(const ushort4*)(gmp + s);
    ushort4 mZ = *(const ushort4*)(gmp + SQ + s);
    ushort4 mN = *(const ushort4*)(gmp + 2 * SQ + s);
    float4 cbR = *(const float4*)(cbias + s);
    float4 cbZ = *(const float4*)(cbias + SQ + s);
    float4 cbN = *(const float4*)(cbias + 2 * SQ + s);
    float4 bhR = *(const float4*)(bhh + s);
    float4 bhZ = *(const float4*)(bhh + SQ + s);
    float4 bhN = *(const float4*)(bhh + 2 * SQ + s);
    float4 wv  = *(const float4*)(Wa + (long)e * SQ + s);

    float4 hn4;
    float dot = 0.f;

#define GRU0_COMP(c, u)                                                       \
    {                                                                         \
        float rg = sigmoidf(b2f(nR.u) + b2f(mR.u) + cbR.c + bhR.c);           \
        float zg = sigmoidf(b2f(nZ.u) + b2f(mZ.u) + cbZ.c + bhZ.c);           \
        float nn = tanhf(b2f(nN.u) + b2f(mN.u) + cbN.c + rg * bhN.c);         \
        float hn = (1.f - zg) * nn;                                           \
        hn4.c = hn;                                                           \
        dot += hn * wv.c;                                                     \
    }
    GRU0_COMP(x, x) GRU0_COMP(y, y) GRU0_COMP(z, z) GRU0_COMP(w, w)
#undef GRU0_COMP

    ushort4 hb4;
    hb4.x = (u16)bh(hn4.x); hb4.y = (u16)bh(hn4.y);
    hb4.z = (u16)bh(hn4.z); hb4.w = (u16)bh(hn4.w);
    *(ushort4*)(hpb + s) = hb4;

    for (int off = 32; off > 0; off >>= 1) dot += __shfl_down(dot, off);
    __shared__ float red[4];
    if ((threadIdx.x & 63) == 0) red[threadIdx.x >> 6] = dot;
    __syncthreads();
    if (threadIdx.x == 0) {
        float tot = red[0] + red[1] + red[2] + red[3] + ba[e];
        gs[((bt * 12 + ni) * 12 + mi) * EQ + e] = sigmoidf(tot);
    }
}

// ---------- gs finalize for tt=1..3 (run once, before outputs) ----------
__global__ void gs_fin_all(const float* __restrict__ gs_part, const float* __restrict__ ba,
                           float* __restrict__ gs)
{
    int idx = blockIdx.x * 256 + threadIdx.x;
    if (idx >= 3 * 2048) return;
    const int tt = 1 + (idx >> 11);
    const int row = idx & 2047;
    if (row >= NROWS) return;
    float s = 0.f;
#pragma unroll
    for (int j = 0; j < 16; ++j) s += gs_part[((long)tt * 2048 + row) * 16 + j];
    const int e = row / BNN;
    const int rr = row - e * BNN;
    const int b_ = rr / 144;
    const int ni = (rr / 12) % 12;
    const int mi = rr % 12;
    const int bt = b_ * TQ + tt;
    gs[((bt * 12 + ni) * 12 + mi) * EQ + e] = sigmoidf(s + ba[e]);
}

// ---------- generic split-K reduce ----------
__global__ __launch_bounds__(256)
void reduce_k(const float* __restrict__ part, int ksplit, int mn, int Nn,
              const float* __restrict__ bias, long sBiasB, int act,
              float* __restrict__ Cf, long sCfB, int ldcf,
              u16* __restrict__ Cb, long sCbB, int ldcb)
{
    int i4 = blockIdx.x * 256 + threadIdx.x;
    int total4 = mn >> 2;
    if (i4 >= total4) return;
    int b = blockIdx.y;
    const float4* p4 = (const float4*)part;
    float4 s = make_float4(0.f, 0.f, 0.f, 0.f);
    for (int ks = 0; ks < ksplit; ++ks) {
        float4 v = p4[(long)(b * ksplit + ks) * total4 + i4];
        s.x += v.x; s.y += v.y; s.z += v.z; s.w += v.w;
    }
    int i = i4 << 2;
    int r = i / Nn, c = i % Nn;
    if (bias) {
        float4 bv = *(const float4*)(bias + (long)b * sBiasB + c);
        s.x += bv.x; s.y += bv.y; s.z += bv.z; s.w += bv.w;
    }
    if (act == 1) {
        s.x = sigmoidf(s.x); s.y = sigmoidf(s.y); s.z = sigmoidf(s.z); s.w = sigmoidf(s.w);
    } else if (act == 2) {
        s.x = tanhf(s.x); s.y = tanhf(s.y); s.z = tanhf(s.z); s.w = tanhf(s.w);
    }
    if (Cf) *(float4*)(Cf + (long)b * sCfB + (long)r * ldcf + c) = s;
    if (Cb) {
        ushort4 o;
        o.x = (u16)bh(s.x); o.y = (u16)bh(s.y); o.z = (u16)bh(s.z); o.w = (u16)bh(s.w);
        *(ushort4*)(Cb + (long)b * sCbB + (long)r * ldcb + c) = o;
    }
}

// ---------- fused rz split-K reduce + sigmoid + ahat + zbuf ----------
__global__ __launch_bounds__(256)
void rz_ahat_k(const float* __restrict__ part, const float* __restrict__ brz,
               const float* __restrict__ prop, u16* __restrict__ amat_b,
               float* __restrict__ zbuf)
{
    int i = blockIdx.x * 256 + threadIdx.x;
    int rrow = i >> 10, c = i & 1023;
    float sr = 0.f, sz = 0.f;
#pragma unroll
    for (int ks = 0; ks < 8; ++ks) {
        const float* p = part + (long)ks * 196608 + (long)rrow * 2048;
        sr += p[c]; sz += p[1024 + c];
    }
    float r = sigmoidf(sr + brz[c]);
    float z = sigmoidf(sz + brz[1024 + c]);
    amat_b[(long)rrow * 2048 + 1024 + c] = (u16)bh(r * prop[i]);
    zbuf[i] = z;
}

// ---------- fused hhat split-K reduce + tanh + prop update ----------
__global__ __launch_bounds__(256)
void hhat_prop_k(const float* __restrict__ part, const float* __restrict__ bh_,
                 const float* __restrict__ zbuf,
                 float* __restrict__ prop, u16* __restrict__ prop_b)
{
    int i = blockIdx.x * 256 + threadIdx.x;
    float s = 0.f;
#pragma unroll
    for (int ks = 0; ks < 8; ++ks) s += part[(long)ks * 98304 + i];
    float hhat = tanhf(s + bh_[i & 1023]);
    float z = zbuf[i];
    float v = (1.f - z) * prop[i] + z * hhat;
    prop[i] = v;
    prop_b[i] = (u16)bh(v);
}

// ---------- fused 3-buffer fp32 -> bf16 convert ----------
__global__ void cvt3_bf16_k(const float* __restrict__ s0, u16* __restrict__ d0, int n0,
                            const float* __restrict__ s1, u16* __restrict__ d1, int n1,
                            const float* __restrict__ s2, u16* __restrict__ d2, int n2)
{
    int i = blockIdx.x * 256 + threadIdx.x;
    const float* s; u16* d; int base;
    if (i < n0) { s = s0; d = d0; base = i; }
    else if (i < n0 + n1) { s = s1; d = d1; base = i - n0; }
    else if (i < n0 + n1 + n2) { s = s2; d = d2; base = i - n0 - n1; }
    else return;
    float4 v = ((const float4*)s)[base];
    ushort4 o;
    o.x = (u16)bh(v.x); o.y = (u16)bh(v.y); o.z = (u16)bh(v.z); o.w = (u16)bh(v.w);
    ((ushort4*)d)[base] = o;
}

__global__ __launch_bounds__(256)
void transpose_wc(const float* __restrict__ Wcomp, float* __restrict__ W1T, float* __restrict__ W2T)
{
    __shared__ float t1[32][33];
    __shared__ float t2[32][33];
    const int tx = threadIdx.x & 31;
    const int ty = threadIdx.x >> 5;
    const int d0 = blockIdx.x * 32;
    const int s0 = blockIdx.y * 32;
#pragma unroll
    for (int k = 0; k < 4; ++k) {
        int d = d0 + ty + k * 8;
        t1[ty + k * 8][tx] = Wcomp[(long)d * 2048 + s0 + tx];
        t2[ty + k * 8][tx] = Wcomp[(long)d * 2048 + 1024 + s0 + tx];
    }
    __syncthreads();
#pragma unroll
    for (int k = 0; k < 4; ++k) {
        int s = s0 + ty + k * 8;
        W1T[(long)s * 1024 + d0 + tx] = t1[tx][ty + k * 8];
        W2T[(long)s * 1024 + d0 + tx] = t2[tx][ty + k * 8];
    }
}

__global__ void pack_rz(const float* __restrict__ Wr, const float* __restrict__ Wz,
                        const float* __restrict__ br, const float* __restrict__ bz,
                        u16* __restrict__ Wrz, float* __restrict__ brz)
{
    int i4 = blockIdx.x * 256 + threadIdx.x;
    if (i4 < 512) {
        int c = i4 * 4;
        float4 b = (c < 1024) ? *(const float4*)(br + c) : *(const float4*)(bz + c - 1024);
        *(float4*)(brz + c) = b;
    }
    if (i4 >= 1048576) return;
    int i = i4 * 4;
    int j = i >> 11;
    int c = i & 2047;
    float4 v = (j < 1024) ? *(const float4*)(Wr + (long)j * 2048 + c)
                          : *(const float4*)(Wz + (long)(j - 1024) * 2048 + c);
    ushort4 o;
    o.x = (u16)bh(v.x); o.y = (u16)bh(v.y); o.z = (u16)bh(v.z); o.w = (u16)bh(v.w);
    *(ushort4*)(Wrz + i) = o;
}

__global__ void cbias_k(const float* __restrict__ Wih, const float* __restrict__ bih,
                        const float* __restrict__ bcomp, float* __restrict__ cbias)
{
    int g = blockIdx.x * blockDim.x + threadIdx.x;
    if (g >= G3S) return;
    const float* w = Wih + (long)g * SQ;
    float s = 0.f;
    for (int k = 0; k < SQ; k += 4) {
        float4 wv = *(const float4*)(w + k);
        float4 bv = *(const float4*)(bcomp + k);
        s += wv.x * bv.x + wv.y * bv.y + wv.z * bv.z + wv.w * bv.w;
    }
    cbias[g] = s + bih[g];
}

// ---------------- merged + amat fused (+ inline gs finalize for tt != 0) ----------------
__global__ __launch_bounds__(256)
void merged_amat_k(const float* __restrict__ gs, const float* __restrict__ gs_part,
                   const float* __restrict__ ba,
                   const u16* __restrict__ msgs_b,
                   const float* __restrict__ prop, u16* __restrict__ amat_b)
{
    const int bn = blockIdx.x;   // bt*12+n
    const int bt = bn / 12;
    const int n = bn - bt * 12;
    const int b_ = bt / TQ;
    const int tt = bt - b_ * TQ;
    __shared__ float g[84];
    if (threadIdx.x < 84) {
        const int m = threadIdx.x / 7;
        const int e = threadIdx.x - m * 7;
        float val;
        if (tt == 0) {
            val = gs[bn * 84 + threadIdx.x];
        } else {
            const int row = e * BNN + b_ * 144 + n * 12 + m;
            float s = 0.f;
#pragma unroll
            for (int j = 0; j < 16; ++j) s += gs_part[((long)tt * 2048 + row) * 16 + j];
            val = sigmoidf(s + ba[e]);
        }
        g[threadIdx.x] = val;
    }
    __syncthreads();
    const int s = threadIdx.x * 4;
    float4 acc = make_float4(0.f, 0.f, 0.f, 0.f);
    for (int j = 0; j < 84; ++j) {
        const ushort4 mv = *(const ushort4*)(msgs_b + ((long)(bt * 84 + j)) * SQ + s);
        float gj = g[j];
        acc.x += gj * b2f(mv.x);
        acc.y += gj * b2f(mv.y);
        acc.z += gj * b2f(mv.z);
        acc.w += gj * b2f(mv.w);
    }
    ushort4 o;
    o.x = (u16)bh(acc.x); o.y = (u16)bh(acc.y); o.z = (u16)bh(acc.z); o.w = (u16)bh(acc.w);
    *(ushort4*)(amat_b + (long)bn * 2048 + s) = o;
    float4 pv = *(const float4*)(prop + (long)bn * SQ + s);
    ushort4 o2;
    o2.x = (u16)bh(pv.x); o2.y = (u16)bh(pv.y); o2.z = (u16)bh(pv.z); o2.w = (u16)bh(pv.w);
    *(ushort4*)(amat_b + (long)bn * 2048 + 1024 + s) = o2;
}

// ---------------- final outputs ----------------
__global__ __launch_bounds__(256)
void outputs_k(const float* __restrict__ gs, float* __restrict__ out)
{
    __shared__ float s_act[672];
    __shared__ float s_asum[96];
    int tid = threadIdx.x;
    for (int idx = tid; idx < 672; idx += 256) {
        int bn = idx / 7, e = idx % 7;
        float sum = 0.f;
        for (int m = 0; m < 12; ++m) {
            float g0 = gs[bn * 84 + m * 7];
            sum += (1.f - g0) * gs[bn * 84 + m * 7 + e];
        }
        s_act[idx] = sum;
        out[idx] = sum;
    }
    for (int idx = tid; idx < 96; idx += 256) {
        float a = 0.f;
        for (int m = 0; m < 12; ++m) a += 1.f - gs[idx * 84 + m * 7];
        s_asum[idx] = a;
    }
    for (int idx = tid; idx < 1152; idx += 256) {
        int bn = idx / 12, m = idx % 12;
        out[720 + idx] = 1.f - gs[bn * 84 + m * 7];
    }
    __syncthreads();
    if (tid < 8) {
        float tmp[6];
        float mx = -1e30f;
        for (int e = 1; e < 7; ++e) {
            float sum = 0.f;
            for (int n = 0; n < 12; ++n) {
                int bn = tid * 12 + n;
                sum += s_act[bn * 7 + e] * s_asum[bn];
            }
            tmp[e - 1] = sum;
            mx = fmaxf(mx, sum);
        }
        float den = 0.f;
        for (int e = 0; e < 6; ++e) { tmp[e] = expf(tmp[e] - mx); den += tmp[e]; }
        for (int e = 0; e < 6; ++e) out[672 + tid * 6 + e] = tmp[e] / den;
    }
}

// ---------------- host ----------------
template<int AS32, int BS32>
static void launch_gemm(const void* A, long sAb, int lda,
                        const void* B, long sBb, int ldb,
                        const float* bias, long sBiasb,
                        float* C, long sCb, int ldc,
                        u16* Cb, long sCbb, int ldcb,
                        int M, int Nn, int K, int act, int batch, int ksplit,
                        hipStream_t stream)
{
    dim3 grid((M + 63) / 64, (Nn + 127) / 128, batch * ksplit);
    gemm_mfma<AS32, BS32><<<grid, dim3(256), 0, stream>>>(
        A, sAb, lda, B, sBb, ldb, bias, sBiasb, C, sCb, ldc, Cb, sCbb, ldcb,
        M, Nn, K, act, ksplit);
}

extern "C" void kernel_launch(void* const* d_in, const int* in_sizes, int n_in,
                              void* d_out, int out_size, void* d_ws, size_t ws_size,
                              hipStream_t stream)
{
    const float* pose  = (const float*)d_in[0];
    const float* Wc    = (const float*)d_in[5];
    const float* bc    = (const float*)d_in[6];
    const float* We    = (const float*)d_in[7];
    const float* be    = (const float*)d_in[8];
    const float* Wcomp = (const float*)d_in[9];
    const float* bcomp = (const float*)d_in[10];
    const float* Wr    = (const float*)d_in[11];
    const float* br    = (const float*)d_in[12];
    const float* Wz    = (const float*)d_in[13];
    const float* bz    = (const float*)d_in[14];
    const float* Wh    = (const float*)d_in[15];
    const float* bh_   = (const float*)d_in[16];
    const float* Wih   = (const float*)d_in[17];
    const float* Whh   = (const float*)d_in[18];
    const float* bih   = (const float*)d_in[19];
    const float* bhh   = (const float*)d_in[20];
    const float* Wa    = (const float*)d_in[21];
    const float* ba    = (const float*)d_in[22];

    float* ws = (float*)d_ws;
    // fp32 region
    float* prop    = ws;                    // 98304
    float* cbias   = prop + 98304;          // 3072
    float* scratch = cbias + 3072;          // 8257536
    float* gs      = scratch + 8257536;     // 8064
    float* zbuf    = gs + 8064;             // 98304
    float* brz     = zbuf + 98304;          // 2048
    float* gs_part = brz + 2048;            // 131072 (4 x 2048 x 16)
    float* fend    = gs_part + 131072;
    // bf16 region
    u16* Whh_b  = (u16*)fend;               // 3145728
    u16* Wnm_b  = Whh_b + 3145728;          // 6291456
    u16* Wrz_b  = Wnm_b + 6291456;          // 4194304
    u16* Gnm_b  = Wrz_b + 4194304;          // 4128768
    u16* msgs_b = Gnm_b + 4128768;          // 688128
    u16* h_b0   = msgs_b + 688128;          // 2064384
    u16* h_b1   = h_b0 + 2064384;           // 2064384
    u16* prop_b = h_b1 + 2064384;           // 98304
    u16* amat_b = prop_b + 98304;           // 196608
    u16* pose_b = amat_b + 196608;          // 2534400
    u16* Wc_b   = pose_b + 2534400;         // 27033600

    float* W1T = scratch;                   // transient
    float* W2T = scratch + 1048576;         // transient

    // ---- once per call ----
    hipLaunchKernelGGL(cvt3_bf16_k, dim3(31947), dim3(256), 0, stream,
                       Whh, Whh_b, 786432, pose, pose_b, 633600, Wc, Wc_b, 6758400);
    hipLaunchKernelGGL(cbias_k, dim3(12), dim3(256), 0, stream, Wih, bih, bcomp, cbias);
    hipLaunchKernelGGL(transpose_wc, dim3(32, 32), dim3(256), 0, stream, Wcomp, W1T, W2T);
    hipLaunchKernelGGL(pack_rz, dim3(4096), dim3(256), 0, stream, Wr, Wz, br, bz, Wrz_b, brz);
    gemm128_f32<<<dim3(24, 8, 1), dim3(256), 0, stream>>>(
        Wih, SQ, W1T, SQ, nullptr, 0, SQ, Wnm_b, SQ, G3S, SQ, SQ, 1);
    gemm128_f32<<<dim3(24, 8, 1), dim3(256), 0, stream>>>(
        Wih, SQ, W2T, SQ, nullptr, 0, SQ, Wnm_b + (long)G3S * SQ, SQ, G3S, SQ, SQ, 1);
    // prop = pose @ Wc^T + bc : bf16 operands, ksplit=55
    launch_gemm<0, 0>(pose_b, 0, DIN, Wc_b, 0, DIN, nullptr, 0,
                      scratch, 98304, SQ, nullptr, 0, 0, 96, SQ, DIN, 0, 1, 55, stream);
    hipLaunchKernelGGL(reduce_k, dim3(96, 1), dim3(256), 0, stream,
                       scratch, 55, 98304, SQ, bc, 0L, 0,
                       prop, 0L, SQ, prop_b, 0L, SQ);

    for (int t = 0; t <= TSQ; ++t) {
        // msgs[bt,n,e,s] = prop @ We[e]^T + be[e] : batch 7, ksplit 4
        launch_gemm<0, 1>(prop_b, 0, SQ, We, (long)SQ * SQ, SQ, nullptr, 0,
                          scratch, 98304, SQ, nullptr, 0, 0, 96, SQ, SQ, 0, EQ, 4, stream);
        hipLaunchKernelGGL(reduce_k, dim3(96, EQ), dim3(256), 0, stream,
                           scratch, 4, 98304, SQ, be, (long)SQ, 0,
                           (float*)nullptr, 0L, 0, msgs_b, (long)SQ, EQ * SQ);
        // Gnm = msgs_e @ Wnm^T : batch 7, direct bf16 write
        launch_gemm<0, 0>(msgs_b, SQ, EQ * SQ, Wnm_b, 0, SQ, nullptr, 0,
                          nullptr, 0, 0, Gnm_b, 589824, 6 * SQ, 96, 6 * SQ, SQ, 0, EQ, 1, stream);
        // GRU scan: tt=0 elementwise, then 3 fused GEMM steps (bf16-carried h)
        hipLaunchKernelGGL(gru0, dim3(NROWS), dim3(256), 0, stream,
                           Gnm_b, cbias, bhh, h_b0, Wa, ba, gs);
        for (int tt = 1; tt < TQ; ++tt) {
            const u16* hin = (tt & 1) ? h_b0 : h_b1;
            u16* hout = (tt & 1) ? h_b1 : h_b0;
            hipLaunchKernelGGL(gh_gru, dim3(256), dim3(512), 0, stream,
                               hin, Whh_b, bhh, Gnm_b, cbias, hout, Wa, gs_part, tt);
        }
        if (t < TSQ) {
            // merged+amat with inline gs finalize (reads gs_part for tt != 0)
            hipLaunchKernelGGL(merged_amat_k, dim3(96), dim3(256), 0, stream,
                               gs, gs_part, ba, msgs_b, prop, amat_b);
            // rz partials : ksplit=8
            launch_gemm<0, 0>(amat_b, 0, 2 * SQ, Wrz_b, 0, 2 * SQ, nullptr, 0,
                              scratch, 196608, 2 * SQ, nullptr, 0, 0, 96, 2 * SQ, 2 * SQ, 0, 1, 8, stream);
            hipLaunchKernelGGL(rz_ahat_k, dim3(384), dim3(256), 0, stream,
                               scratch, brz, prop, amat_b, zbuf);
            // hhat partials : ksplit=8
            launch_gemm<0, 1>(amat_b, 0, 2 * SQ, Wh, 0, 2 * SQ, nullptr, 0,
                              scratch, 98304, SQ, nullptr, 0, 0, 96, SQ, 2 * SQ, 0, 1, 8, stream);
            hipLaunchKernelGGL(hhat_prop_k, dim3(384), dim3(256), 0, stream,
                               scratch, bh_, zbuf, prop, prop_b);
        }
    }

    // finalize gs for tt=1..3 of the LAST t, then outputs
    hipLaunchKernelGGL(gs_fin_all, dim3(24), dim3(256), 0, stream, gs_part, ba, gs);
    hipLaunchKernelGGL(outputs_k, dim3(1), dim3(256), 0, stream, gs, (float*)d_out);
}